// Round 1
// baseline (43956.076 us; speedup 1.0000x reference)
//
#include <hip/hip_runtime.h>
#include <hip/hip_cooperative_groups.h>
#include <hip/hip_bf16.h>
#include <math.h>

namespace cg = cooperative_groups;

#define NN 65536
#define MATD 131072L   // doubles per complex matrix (re plane + im plane)
#define MAT0 32768L    // header size in doubles

// ws header offsets (doubles)
#define SC_DT 0
#define SC_NUINV 3
#define SC_EXPM_S 4
#define SC_EXPM_SCALE 5
#define SC_NORMS2 6
#define SC_MU 7
// 8,9: n1,ninf of M ; 10,11: n1,ninf of M^-1 ; 12,13: n1,ninf of S ; 14: F^2 of S
#define W_UNIT_RE 64
#define W_UNIT_IM 320
#define W_C_RE 576
#define W_C_IM 832
#define W_LD_RE 1088
#define W_LD_IM 1344
#define W_SU 1600
#define W_SLOT 1856
#define W_SLOTU 2112        // 256 entries -> ends 2368
#define W_W 2432            // 256*33*2 doubles -> ends 19328
#define FLAGBASE 20480      // (legacy) 1 double per inversion
#define TRBASE 22528        // 96 doubles per inversion (2 per NS iter, <=48 iters)
#define NRM_ROW 30208       // 256 row-sum partials
#define NRM_COL 30464       // 256 col-sum partials
#define NRM_DEV 30720       // 256 row sums of |M - I|
#define NPOOL 256           // virtual pool capacity (every unit can be pooled)

// matrix slots
#define S_EW 0
#define S_NUW 1
#define S_LAT 2
#define S_T2 3
#define S_T3 4
#define S_T4 5
#define S_E1 6
#define S_E2 7
#define S_M 8
#define S_M2 9
#define S_Y 10
#define S_Y2 11
#define S_IY 12
#define S_X 13
#define S_X2 14
#define S_T 15
#define S_W 16
#define S_V 17
#define S_G 18
#define S_G2 19
#define PBASE 20            // S^k at PBASE+k-1, k=1..32 -> 20..51
#define POOL0 52            // physical pool: A at 52..52+K-1, B at 52+K..52+2K-1

#define PI_D 3.14159265358979323846

__device__ inline double ldin(const void* p, int i, int dt){
    if (dt == 0) return (double)__bfloat162float(((const __hip_bfloat16*)p)[i]);
    if (dt == 1) return (double)((const float*)p)[i];
    return ((const double*)p)[i];
}

// ---------------- init: zero header ----------------
__global__ __launch_bounds__(256) void k_init(double* ws){
    ws[blockIdx.x * 256 + threadIdx.x] = 0.0;   // grid 128 -> 32768
}

// ---------------- input dtype detection ----------------
__global__ __launch_bounds__(64) void k_detect(const void* x, double* ws){
    __shared__ int ok[3];
    int t = threadIdx.x;
    if (t < 3) ok[t] = 1;
    __syncthreads();
    const __hip_bfloat16* pb = (const __hip_bfloat16*)x;
    for (int k = t; k < 256; k += 64){
        float v = __bfloat162float(pb[k]);
        if (!(v > 0.40f && v < 1.60f)) ok[0] = 0;
    }
    const float* pf = (const float*)x;
    { float v = pf[t]; if (!(v > 0.40f && v < 1.60f)) ok[1] = 0; }
    const double* pd = (const double*)x;
    { double v = pd[t]; if (!(v > 0.40 && v < 1.60)) ok[2] = 0; }
    __syncthreads();
    if (t == 0) ws[SC_DT] = ok[0] ? 0.0 : (ok[1] ? 1.0 : 2.0);
}

// ---------------- small vector stage (1 block) ----------------
__global__ __launch_bounds__(256) void k_small(
    const void* xin, const void* Ar, const void* Ai,
    const void* cAr, const void* cAi,
    double* ws, float* out)
{
    __shared__ double xs[256], twc[256], tws[256], ur[256], ui[256], red[256];
    int t = threadIdx.x;
    int dt = (int)ws[SC_DT];
    double x = ldin(xin, t, dt);
    xs[t] = x;
    red[t] = log(x);
    double ang = -2.0 * PI_D * (double)t / 256.0;
    twc[t] = cos(ang); tws[t] = sin(ang);
    __syncthreads();
    for (int s = 128; s > 0; s >>= 1){ if (t < s) red[t] += red[t+s]; __syncthreads(); }
    double slog = red[0];
    __syncthreads();
    double dy = (t == 0) ? 0.0 : (x - xs[t-1]);
    double r = x * exp(-slog / 256.0);
    double unr = r * cos(dy), uni = r * sin(dy);
    ur[t] = unr; ui[t] = uni;
    ws[W_UNIT_RE + t] = unr; ws[W_UNIT_IM + t] = uni;
    __syncthreads();
    double fr = 0.0, fi = 0.0;
    for (int n = 0; n < 256; n++){
        int m = (t * n) & 255;
        double c = twc[m], s = tws[m];
        fr += ur[n]*c - ui[n]*s;
        fi += ur[n]*s + ui[n]*c;
    }
    red[t] = fr; __syncthreads();
    for (int s = 128; s > 0; s >>= 1){ if (t < s) red[t] += red[t+s]; __syncthreads(); }
    double sr = red[0]; __syncthreads();
    red[t] = fi; __syncthreads();
    for (int s = 128; s > 0; s >>= 1){ if (t < s) red[t] += red[t+s]; __syncthreads(); }
    double si = red[0];
    double den = sr*sr + si*si;
    double cr = (fr*sr + fi*si) / den, ci = (fi*sr - fr*si) / den;
    ws[W_C_RE + t] = cr; ws[W_C_IM + t] = ci;
    double ar = ldin(Ar, t, dt), ai = ldin(Ai, t, dt);
    double car = ldin(cAr, t, dt), cai = ldin(cAi, t, dt);
    double pr = ar*unr - ai*uni, pi = ar*uni + ai*unr;
    double qr = car*pr + cai*pi, qi = car*pi - cai*pr;
    out[t] = (float)(x + atan2(qi, qr));
    double ldr = 0.5 * log((qr*qr + qi*qi) / (unr*unr + uni*uni));
    double ldi = atan2(qi, qr) - atan2(uni, unr);
    ws[W_LD_RE + t] = ldr; ws[W_LD_IM + t] = ldi;
}

// ---------------- build Ew and new_uw (fp64 planes) ----------------
__global__ __launch_bounds__(256) void k_build_mats(
    const void* Ewr, const void* Ewi, const void* uwr, const void* uwi, double* ws)
{
    int ij = blockIdx.x * 256 + threadIdx.x;
    int i = ij >> 8, j = ij & 255;
    int dt = (int)ws[SC_DT];
    double* EW = ws + MAT0 + (size_t)S_EW * MATD;
    EW[ij] = ldin(Ewr, ij, dt); EW[NN + ij] = ldin(Ewi, ij, dt);
    double* U = ws + MAT0 + (size_t)S_NUW * MATD;
    if (i == 0){ U[ij] = ws[W_LD_RE + j]; U[NN + ij] = ws[W_LD_IM + j]; }
    else { int src = (i-1)*256 + j; U[ij] = ldin(uwr, src, dt); U[NN + ij] = ldin(uwi, src, dt); }
}

// ---------------- norms: ws[idx]=n1, ws[idx+1]=ninf, ws[SC_NUINV]=1/(n1*ninf) ----
__global__ __launch_bounds__(256) void k_norm1inf(const double* M, double* ws, int idx)
{
    __shared__ double cs[256], rs[256];
    int t = threadIdx.x;
    double c = 0.0, r = 0.0;
    for (int i = 0; i < 256; i++){
        c += fabs(M[i*256 + t]) + fabs(M[NN + i*256 + t]);
        r += fabs(M[t*256 + i]) + fabs(M[NN + t*256 + i]);
    }
    cs[t] = c; rs[t] = r; __syncthreads();
    for (int s = 128; s > 0; s >>= 1){
        if (t < s){ cs[t] = fmax(cs[t], cs[t+s]); rs[t] = fmax(rs[t], rs[t+s]); }
        __syncthreads();
    }
    if (t == 0){
        ws[idx] = cs[0]; ws[idx+1] = rs[0];
        ws[SC_NUINV] = 1.0 / (cs[0] * rs[0]);
    }
}

// Frobenius^2 -> ws[14]
__global__ __launch_bounds__(256) void k_fro(const double* M, double* ws)
{
    __shared__ double red[256];
    int t = threadIdx.x;
    double s = 0.0;
    for (int i = 0; i < 256; i++){
        double a = M[i*256 + t], b = M[NN + i*256 + t];
        s += a*a + b*b;
    }
    red[t] = s; __syncthreads();
    for (int k = 128; k > 0; k >>= 1){ if (t < k) red[t] += red[t+k]; __syncthreads(); }
    if (t == 0) ws[14] = red[0];
}

// rigorous sigma_max upper bound: min( sqrt(n1*ninf), ||S||_F )
__global__ void k_snorm(double* ws)
{
    double b1 = sqrt(ws[12] * ws[13]);
    double b2 = sqrt(ws[14]);
    ws[SC_NORMS2] = fmin(b1, b2);
}

// ---------------- complex GEMM (host-launched; expm path) ----------------
// C = alpha*preA(A)*preB(B) + beta*D + gamma*I
// preA: 0 none, 1 conj, 2 (A-I).  preB: 0 none, 1 (2I-B).
// fm: 0 normal; 1 expm-squaring (round>ws[SC_EXPM_S] -> copy A)
__global__ __launch_bounds__(256) void k_zgemm(
    const double* __restrict__ Ab, const double* __restrict__ Bb,
    double* __restrict__ Cb, const double* __restrict__ Db,
    int preA, int preB, double alpha, double beta, double gamma,
    double* __restrict__ ws, int fm, int round, int flagIdx, int trIdx,
    long sA, long sB, long sC)
{
    int z = blockIdx.z;
    const double* A = Ab + (size_t)z * sA;
    const double* B = Bb + (size_t)z * sB;
    double* C = Cb + (size_t)z * sC;
    int tx = threadIdx.x & 15, ty = threadIdx.x >> 4;
    int row = blockIdx.y * 16 + ty, col = blockIdx.x * 16 + tx;
    if (fm == 1 && round > (int)ws[SC_EXPM_S]){
        C[row*256 + col] = A[row*256 + col];
        C[NN + row*256 + col] = A[NN + row*256 + col];
        return;
    }
    __shared__ double Asr[16][17], Asi[16][17], Bsr[16][17], Bsi[16][17];
    double cr = 0.0, ci = 0.0;
    for (int k0 = 0; k0 < 256; k0 += 16){
        int ac = k0 + tx;
        double a_re = A[row*256 + ac], a_im = A[NN + row*256 + ac];
        if (preA == 1) a_im = -a_im;
        else if (preA == 2){ if (row == ac) a_re -= 1.0; }
        int br = k0 + ty;
        double b_re = B[br*256 + col], b_im = B[NN + br*256 + col];
        if (preB == 1){ b_re = ((br == col) ? 2.0 : 0.0) - b_re; b_im = -b_im; }
        Asr[ty][tx] = a_re; Asi[ty][tx] = a_im;
        Bsr[ty][tx] = b_re; Bsi[ty][tx] = b_im;
        __syncthreads();
        #pragma unroll
        for (int kk = 0; kk < 16; kk++){
            double xr = Asr[ty][kk], xi = Asi[ty][kk];
            double yr = Bsr[kk][tx], yi = Bsi[kk][tx];
            cr += xr*yr - xi*yi;
            ci += xr*yi + xi*yr;
        }
        __syncthreads();
    }
    double outr = alpha * cr, outi = alpha * ci;
    if (Db){ outr += beta * Db[row*256 + col]; outi += beta * Db[NN + row*256 + col]; }
    if (row == col) outr += gamma;
    C[row*256 + col] = outr;
    C[NN + row*256 + col] = outi;
}

// ---- elementwise: C = a1*f1*X1 + a2*f2*X2 + a3*X3 + a4*X4 + g*I
// mode: 0 none; 1 f1=expm scale; 2 f1=mu,f2=1/mu; 3 f1=mu^2,f2=1/mu^2
__global__ __launch_bounds__(256) void k_combine(double* ws, int dst,
    int s1, int s2, int s3, int s4,
    double a1, double a2, double a3, double a4, double g, int mode)
{
    int ij = blockIdx.x * 256 + threadIdx.x;
    int i = ij >> 8, j = ij & 255;
    double f1 = 1.0, f2 = 1.0;
    if (mode == 1){ f1 = ws[SC_EXPM_SCALE]; }
    else if (mode == 2){ double mu = ws[SC_MU]; f1 = mu; f2 = 1.0/mu; }
    else if (mode == 3){ double mu = ws[SC_MU]; f1 = mu*mu; f2 = 1.0/(mu*mu); }
    double* C = ws + MAT0 + (size_t)dst * MATD;
    double r = 0.0, m = 0.0;
    if (s1 >= 0){ const double* X = ws + MAT0 + (size_t)s1 * MATD; r += a1*f1*X[ij]; m += a1*f1*X[NN+ij]; }
    if (s2 >= 0){ const double* X = ws + MAT0 + (size_t)s2 * MATD; r += a2*f2*X[ij]; m += a2*f2*X[NN+ij]; }
    if (s3 >= 0){ const double* X = ws + MAT0 + (size_t)s3 * MATD; r += a3*X[ij]; m += a3*X[NN+ij]; }
    if (s4 >= 0){ const double* X = ws + MAT0 + (size_t)s4 * MATD; r += a4*X[ij]; m += a4*X[NN+ij]; }
    if (i == j) r += g;
    C[ij] = r; C[NN + ij] = m;
}

__global__ void k_expm_prep(double* ws)
{
    if (threadIdx.x == 0 && blockIdx.x == 0){
        double n1 = ws[8];
        int s = 0;
        if (n1 > 0.5){
            s = (int)ceil(log2(n1 / 0.5));
            if (s < 0) s = 0; if (s > 10) s = 10;
        }
        ws[SC_EXPM_S] = (double)s;
        ws[SC_EXPM_SCALE] = ldexp(1.0, -s);
    }
}

// ==================== cooperative logm kernel ====================
// Replaces the ~4400-dispatch logm phase: 6 DB-sqrt stages (with NS
// inversions), Cayley, deg-39 artanh, and build_S -- one launch,
// grid.sync() between dependent phases, true early exit for NS and DB.
struct ShMem {
    double Ar[16][17], Ai[16][17], Br[16][17], Bi[16][17];
    double red[256];
};

__global__ __launch_bounds__(256, 1) void k_logm_coop(double* __restrict__ ws)
{
    cg::grid_group grid = cg::this_grid();
    __shared__ ShMem sh;
    const int t = threadIdx.x;
    const int b = blockIdx.x;
    const int tx = t & 15, ty = t >> 4;
    const int bx = b & 15, by = b >> 4;
    const int row = by*16 + ty, col = bx*16 + tx;
    const int ij = b*256 + t;        // linear elementwise index (ii=b, jj=t)
    const int ii = b, jj = t;

    double* const MB = ws + MAT0;
    auto SL = [&](int s){ return MB + (size_t)s * MATD; };

    auto bsum = [&](double v) -> double {
        sh.red[t] = v; __syncthreads();
        for (int s = 128; s > 0; s >>= 1){ if (t < s) sh.red[t] += sh.red[t+s]; __syncthreads(); }
        double r = sh.red[0]; __syncthreads();
        return r;
    };
    auto bmax = [&](double v) -> double {
        sh.red[t] = v; __syncthreads();
        for (int s = 128; s > 0; s >>= 1){ if (t < s) sh.red[t] = fmax(sh.red[t], sh.red[t+s]); __syncthreads(); }
        double r = sh.red[0]; __syncthreads();
        return r;
    };

    // C = preA(A)*preB(B) (+gamma on diag); optional trace atomicAdd into tr[0..1]
    auto gemm = [&](const double* A, const double* B, double* __restrict__ C,
                    int preA, int preB, double gamma, double* tr){
        double cr = 0.0, ci = 0.0;
        for (int k0 = 0; k0 < 256; k0 += 16){
            int ac = k0 + tx;
            double a_re = A[row*256 + ac], a_im = A[NN + row*256 + ac];
            if (preA == 1) a_im = -a_im;
            else if (preA == 2){ if (row == ac) a_re -= 1.0; }
            int br = k0 + ty;
            double b_re = B[br*256 + col], b_im = B[NN + br*256 + col];
            if (preB == 1){ b_re = ((br == col) ? 2.0 : 0.0) - b_re; b_im = -b_im; }
            sh.Ar[ty][tx] = a_re; sh.Ai[ty][tx] = a_im;
            sh.Br[ty][tx] = b_re; sh.Bi[ty][tx] = b_im;
            __syncthreads();
            #pragma unroll
            for (int kk = 0; kk < 16; kk++){
                double xr = sh.Ar[ty][kk], xi = sh.Ai[ty][kk];
                double yr = sh.Br[kk][tx], yi = sh.Bi[kk][tx];
                cr += xr*yr - xi*yi;
                ci += xr*yi + xi*yr;
            }
            __syncthreads();
        }
        if (row == col) cr += gamma;
        C[row*256 + col] = cr;
        C[NN + row*256 + col] = ci;
        if (tr && row == col){ atomicAdd(tr, cr); atomicAdd(tr + 1, ci); }
    };

    // norm partials of M: block b owns row b and col b (|re|+|im| sums).
    // withDev also writes row sums of |M - I| for DB convergence.
    auto partials = [&](const double* M, bool withDev){
        double mr = M[b*256 + t], mi2 = M[NN + b*256 + t];
        double rv = fabs(mr) + fabs(mi2);
        double cv = fabs(M[t*256 + b]) + fabs(M[NN + t*256 + b]);
        double rs = bsum(rv); if (t == 0) ws[NRM_ROW + b] = rs;
        double cs = bsum(cv); if (t == 0) ws[NRM_COL + b] = cs;
        if (withDev){
            double dv = fabs(mr - ((b == t) ? 1.0 : 0.0)) + fabs(mi2);
            double dsv = bsum(dv); if (t == 0) ws[NRM_DEV + b] = dsv;
        }
    };

    int invid = 0;
    // NS inverse of src (partials of src must already be in NRM_* and synced).
    // Returns buffer (X or X2) holding the inverse; outputs norms of src.
    auto inv = [&](const double* src, double* X, double* X2, double* T,
                   int maxit, double& n1, double& ninf) -> double* {
        n1 = bmax(ws[NRM_COL + t]);
        ninf = bmax(ws[NRM_ROW + t]);
        double nu = 1.0 / (n1 * ninf);
        X[row*256 + col]      =  src[col*256 + row] * nu;      // X0 = conj(src)^T * nu
        X[NN + row*256 + col] = -src[NN + col*256 + row] * nu;
        grid.sync();
        double* xc = X; double* xo = X2;
        for (int i = 0; i < maxit; i++){
            double* tr = ws + (TRBASE + invid*96 + 2*i);       // pre-zeroed by k_init
            gemm(src, xc, T, 0, 0, 0.0, tr);                   // T = M X  (+trace)
            grid.sync();
            double resid = fabs(256.0 - tr[0]) + fabs(tr[1]);
            if (resid < 2.56e-8) break;                        // uniform across grid
            gemm(xc, T, xo, 0, 1, 0.0, nullptr);               // X' = X (2I - T)
            grid.sync();
            double* tm = xc; xc = xo; xo = tm;
        }
        invid++;
        return xc;
    };

    double* Mm = SL(S_M);  double* M2 = SL(S_M2);
    double* Yy = SL(S_Y);  double* Y2 = SL(S_Y2);
    double* X  = SL(S_X);  double* X2 = SL(S_X2);
    double* Tt = SL(S_T);
    double* G  = SL(S_G);  double* G2 = SL(S_G2);
    double* W  = SL(S_W);  double* V  = SL(S_V);
    double* LT = SL(S_LAT);
    double* S  = SL(PBASE);
    double* bcur = SL(S_EW);

    const int DBIT[6] = {22, 12, 10, 10, 8, 8};
    const int NSIT[6] = {44, 24, 20, 18, 16, 16};

    // ---- 6 scaled product-form DB sqrt stages ----
    for (int st = 0; st < 6; st++){
        // stage entry: M = Y = bcur ; norm partials of bcur
        Mm[ij] = bcur[ij]; Mm[NN + ij] = bcur[NN + ij];
        Yy[ij] = bcur[ij]; Yy[NN + ij] = bcur[NN + ij];
        partials(bcur, false);
        grid.sync();
        double* mc = Mm; double* mo = M2; double* yc = Yy; double* yo = Y2;
        for (int it = 0; it < DBIT[st]; it++){
            if (it > 0){
                double dev = bmax(ws[NRM_DEV + t]);    // ||M - I||_inf
                if (dev < 1e-9) break;                 // DB converged
            }
            double nm1, nminf;
            double* iy = inv(mc, X, X2, Tt, NSIT[st], nm1, nminf);
            partials(iy, false);
            grid.sync();
            double ni1 = bmax(ws[NRM_COL + t]);
            double niinf = bmax(ws[NRM_ROW + t]);
            double mu = pow((ni1 * niinf) / (nm1 * nminf), 0.125);
            if (!(mu > 0.125)) mu = 0.125;
            if (mu > 8.0) mu = 8.0;
            double mu2 = mu * mu, rmu = 1.0 / mu, rmu2 = rmu * rmu;
            gemm(yc, iy, G, 0, 0, 0.0, nullptr);       // G = Y * M^-1
            {   // M' = 0.25*(mu^2 M + mu^-2 M^-1) + 0.5 I
                double r  = 0.25 * (mu2 * mc[ij]      + rmu2 * iy[ij]);
                double mi = 0.25 * (mu2 * mc[NN + ij] + rmu2 * iy[NN + ij]);
                if (ii == jj) r += 0.5;
                mo[ij] = r; mo[NN + ij] = mi;
            }
            grid.sync();
            // Y' = 0.5*(mu Y + mu^-1 G) ; partials of M' for next iteration
            yo[ij]      = 0.5 * (mu * yc[ij]      + rmu * G[ij]);
            yo[NN + ij] = 0.5 * (mu * yc[NN + ij] + rmu * G[NN + ij]);
            partials(mo, true);
            grid.sync();
            double* tm = mc; mc = mo; mo = tm;
            tm = yc; yc = yo; yo = tm;
        }
        bcur = yc;
    }

    // ---- Cayley: W = (B - I)(B + I)^-1 ----
    {
        Mm[ij] = bcur[ij] + ((ii == jj) ? 1.0 : 0.0);
        Mm[NN + ij] = bcur[NN + ij];
        // partials of (bcur + I) computed from bcur (Mm not yet grid-visible)
        double rv = fabs(bcur[b*256 + t] + ((b == t) ? 1.0 : 0.0)) + fabs(bcur[NN + b*256 + t]);
        double cv = fabs(bcur[t*256 + b] + ((t == b) ? 1.0 : 0.0)) + fabs(bcur[NN + t*256 + b]);
        double rs = bsum(rv); if (t == 0) ws[NRM_ROW + b] = rs;
        double cs = bsum(cv); if (t == 0) ws[NRM_COL + b] = cs;
    }
    grid.sync();
    double cn1, cninf;
    double* iy = inv(Mm, X, X2, Tt, 20, cn1, cninf);
    gemm(bcur, iy, W, 2, 0, 0.0, nullptr);             // W = (B - I)(B + I)^-1
    grid.sync();
    gemm(W, W, V, 0, 0, 0.0, nullptr);                 // V = W^2
    G[ij] = (ii == jj) ? (1.0/39.0) : 0.0;             // series seed (independent of V)
    G[NN + ij] = 0.0;
    grid.sync();
    // artanh(W) = W * P(V), P = sum_{j=0}^{19} V^j/(2j+1)  (Horner, deg-39 odd)
    double* gc = G; double* go = G2;
    for (int j = 18; j >= 0; j--){
        gemm(V, gc, go, 0, 0, 1.0/(double)(2*j + 1), nullptr);
        grid.sync();
        double* tm = gc; gc = go; go = tm;
    }
    gemm(W, gc, LT, 0, 0, 0.0, nullptr);               // LAT = artanh(W)
    grid.sync();
    // S = 128 * conj(LAT - LAT^T)  -> PBASE (S^1)
    S[ij]      =  128.0 * (LT[ij] - LT[jj*256 + ii]);
    S[NN + ij] = -128.0 * (LT[NN + ij] - LT[NN + jj*256 + ii]);
}

// theta per u (rigorous upper bound); theta>4 -> scaling+squaring pool
__global__ __launch_bounds__(256) void k_theta_pool(double* ws)
{
    __shared__ double th[256]; __shared__ int rk[256];
    int t = threadIdx.x;
    double nS = ws[SC_NORMS2];
    double cr = ws[W_C_RE + t], ci = ws[W_C_IM + t];
    th[t] = sqrt(cr*cr + ci*ci) * nS;
    __syncthreads();
    int r = 0;
    for (int v = 0; v < 256; v++){
        if (th[v] > th[t] || (th[v] == th[t] && v < t)) r++;
    }
    rk[t] = r;
    __syncthreads();
    if (t == 0){
        int cnt = 0;
        for (int u = 0; u < 256; u++){
            double s = 0.0; int slot = -1;
            if (th[u] > 4.0 && rk[u] < NPOOL){
                double e = ceil(log2(th[u] / 4.0));
                if (e < 1.0) e = 1.0; if (e > 12.0) e = 12.0;
                s = e; slot = cnt;
                ws[W_SLOTU + cnt] = (double)u;
                cnt++;
            }
            ws[W_SU + u] = s;
            ws[W_SLOT + u] = (double)slot;
        }
        for (int k = cnt; k < NPOOL; k++) ws[W_SLOTU + k] = -1.0;
    }
}

// weights w[u][k] = (c_u / 2^{s_u})^k / k!
__global__ __launch_bounds__(256) void k_weights(double* ws)
{
    int u = threadIdx.x;
    double sc = ldexp(1.0, -(int)ws[W_SU + u]);
    double cr = ws[W_C_RE + u] * sc, ci = ws[W_C_IM + u] * sc;
    double wr = 1.0, wi = 0.0;
    ws[W_W + (u*33)*2] = 1.0; ws[W_W + (u*33)*2 + 1] = 0.0;
    for (int k = 1; k <= 32; k++){
        double inv = 1.0 / (double)k;
        double nr = (wr*cr - wi*ci) * inv, ni = (wr*ci + wi*cr) * inv;
        wr = nr; wi = ni;
        ws[W_W + (u*33 + k)*2] = wr;
        ws[W_W + (u*33 + k)*2 + 1] = wi;
    }
}

// exp_tens[u] = sum_k w[u][k] S^k -> f32 out (non-pooled, pass 0) or fp64 pool base
__global__ __launch_bounds__(256) void k_combo(double* ws, float* out, long off_ex, int f,
                                               int pass, int K)
{
    __shared__ double wre[16][33], wim[16][33];
    __shared__ int anywork;
    int t = threadIdx.x;
    int row = blockIdx.x, ug = blockIdx.y;
    if (t == 0) anywork = (pass == 0) ? 1 : 0;
    __syncthreads();
    if (pass > 0 && t < 16){
        int u = ug*16 + t;
        int slot = (int)ws[W_SLOT + u];
        int phys = slot - pass * K;
        if (slot >= 0 && phys >= 0 && phys < K) anywork = 1;
    }
    __syncthreads();
    if (!anywork) return;
    for (int i = t; i < 16*33; i += 256){
        int g = i / 33, k = i % 33;
        int u = ug*16 + g;
        wre[g][k] = ws[W_W + (u*33 + k)*2];
        wim[g][k] = ws[W_W + (u*33 + k)*2 + 1];
    }
    __syncthreads();
    int j = t, ij = row*256 + j;
    double ar[16], ai[16];
    #pragma unroll
    for (int g = 0; g < 16; g++){
        ar[g] = (row == j) ? wre[g][0] : 0.0;
        ai[g] = (row == j) ? wim[g][0] : 0.0;
    }
    for (int k = 1; k <= 32; k++){
        const double* SP = ws + MAT0 + (size_t)(PBASE + k - 1) * MATD;
        double sre = SP[ij], sim = SP[NN + ij];
        #pragma unroll
        for (int g = 0; g < 16; g++){
            ar[g] += wre[g][k]*sre - wim[g][k]*sim;
            ai[g] += wre[g][k]*sim + wim[g][k]*sre;
        }
    }
    for (int g = 0; g < 16; g++){
        int u = ug*16 + g;
        int slot = (int)ws[W_SLOT + u];
        if (slot >= 0){
            int phys = slot - pass * K;
            if (phys >= 0 && phys < K){
                double* P = ws + MAT0 + (size_t)(POOL0 + phys) * MATD;
                P[ij] = ar[g]; P[NN + ij] = ai[g];
            }
        } else if (pass == 0){
            long base = off_ex + (long)u * NN * f + (long)ij * f;
            out[base] = (float)ar[g];
            if (f == 2) out[base + 1] = (float)ai[g];
        }
    }
}

// pool squaring: virtual slot = pass*K + z; square only if round <= s_u
__global__ __launch_bounds__(256) void k_pool_sq(double* ws, int round, int pass, int K)
{
    int z = blockIdx.z;
    int vs = pass * K + z;
    int u = (vs < NPOOL) ? (int)ws[W_SLOTU + vs] : -1;
    if (u < 0) return;
    if (round > (int)ws[W_SU + u]) return;
    const double* A = ws + MAT0 + (size_t)(POOL0 + ((round & 1) ? 0 : K) + z) * MATD;
    double* C = ws + MAT0 + (size_t)(POOL0 + ((round & 1) ? K : 0) + z) * MATD;
    int tx = threadIdx.x & 15, ty = threadIdx.x >> 4;
    int row = blockIdx.y*16 + ty, col = blockIdx.x*16 + tx;
    __shared__ double Asr[16][17], Asi[16][17], Bsr[16][17], Bsi[16][17];
    double cr = 0.0, ci = 0.0;
    for (int k0 = 0; k0 < 256; k0 += 16){
        Asr[ty][tx] = A[row*256 + k0 + tx];
        Asi[ty][tx] = A[NN + row*256 + k0 + tx];
        Bsr[ty][tx] = A[(k0 + ty)*256 + col];
        Bsi[ty][tx] = A[NN + (k0 + ty)*256 + col];
        __syncthreads();
        #pragma unroll
        for (int kk = 0; kk < 16; kk++){
            double xr = Asr[ty][kk], xi = Asi[ty][kk];
            double yr = Bsr[kk][tx], yi = Bsi[kk][tx];
            cr += xr*yr - xi*yi;
            ci += xr*yi + xi*yr;
        }
        __syncthreads();
    }
    C[row*256 + col] = cr;
    C[NN + row*256 + col] = ci;
}

__global__ __launch_bounds__(256) void k_pool_out(const double* ws, float* out, long off_ex,
                                                  int f, int pass, int K)
{
    int z = blockIdx.y;
    int vs = pass * K + z;
    int u = (vs < NPOOL) ? (int)ws[W_SLOTU + vs] : -1;
    if (u < 0) return;
    int su = (int)ws[W_SU + u];
    int ij = blockIdx.x * 256 + threadIdx.x;
    const double* P = ws + MAT0 + (size_t)(POOL0 + ((su & 1) ? K : 0) + z) * MATD;
    long base = off_ex + (long)u * NN * f + (long)ij * f;
    out[base] = (float)P[ij];
    if (f == 2) out[base + 1] = (float)P[NN + ij];
}

__global__ __launch_bounds__(256) void k_cast_out(const double* ws, int slot, float* out, long off, int f)
{
    int ij = blockIdx.x * 256 + threadIdx.x;
    const double* P = ws + MAT0 + (size_t)slot * MATD;
    out[off + (long)ij * f] = (float)P[ij];
    if (f == 2) out[off + (long)ij * f + 1] = (float)P[NN + ij];
}

// ============================ host ============================
extern "C" void kernel_launch(void* const* d_in, const int* in_sizes, int n_in,
                              void* d_out, int out_size, void* d_ws, size_t ws_size,
                              hipStream_t stream)
{
    double* ws = (double*)d_ws;
    float* out = (float*)d_out;

    int f = (out_size >= 33816832) ? 2 : 1;
    long off_ex = 256;
    long off_uw = off_ex + (long)f * 16777216L;
    long off_ew = off_uw + (long)f * 65536L;

    k_init<<<128, 256, 0, stream>>>(ws);
    k_detect<<<1, 64, 0, stream>>>(d_in[0], ws);
    k_small<<<1, 256, 0, stream>>>(d_in[0], d_in[1], d_in[2], d_in[3], d_in[4], ws, out);

    long slotsAvail = (long)(ws_size / 8 - MAT0) / MATD;
    if (slotsAvail < POOL0 + 32) return;   // need >= 52 work slots + 16x2 pool (~88.3 MB)
    int K = (int)((slotsAvail - POOL0) / 2);
    if (K > NPOOL) K = NPOOL;
    if (K < 16) K = 16;
    int P = (NPOOL + K - 1) / K;

    auto MP = [&](int s){ return ws + MAT0 + (size_t)s * MATD; };
    auto ZG = [&](int a, int b, int c, int preA, int preB, double al, double be,
                  int d, double ga, int fm, int round){
        k_zgemm<<<dim3(16,16,1), 256, 0, stream>>>(MP(a), MP(b), MP(c),
            d >= 0 ? MP(d) : nullptr, preA, preB, al, be, ga, ws,
            fm, round, 0, 0, 0L, 0L, 0L);
    };
    auto GEMM = [&](int a, int b, int c, int preA, int preB, double al, double be, int d, double ga){
        ZG(a, b, c, preA, preB, al, be, d, ga, 0, 0);
    };

    k_build_mats<<<256, 256, 0, stream>>>(d_in[5], d_in[6], d_in[7], d_in[8], ws);
    k_cast_out<<<256, 256, 0, stream>>>(ws, S_NUW, out, off_uw, f);

    // -------- expm(new_uw): scaling + Paterson-Stockmeyer deg-16 Taylor + squarings ----
    static const double INVF[17] = {
        1.0, 1.0, 0.5, 1.0/6.0, 1.0/24.0, 1.0/120.0, 1.0/720.0, 1.0/5040.0,
        1.0/40320.0, 1.0/362880.0, 1.0/3628800.0, 1.0/39916800.0, 1.0/479001600.0,
        1.0/6227020800.0, 1.0/87178291200.0, 1.0/1307674368000.0, 1.0/20922789888000.0 };
    k_norm1inf<<<1, 256, 0, stream>>>(MP(S_NUW), ws, 8);
    k_expm_prep<<<1, 64, 0, stream>>>(ws);
    k_combine<<<256, 256, 0, stream>>>(ws, S_LAT, S_NUW, -1, -1, -1, 1.0, 0, 0, 0, 0.0, 1); // T = 2^-s NUW
    GEMM(S_LAT, S_LAT, S_T2, 0, 0, 1.0, 0.0, -1, 0.0);
    GEMM(S_T2, S_LAT, S_T3, 0, 0, 1.0, 0.0, -1, 0.0);
    GEMM(S_T2, S_T2, S_T4, 0, 0, 1.0, 0.0, -1, 0.0);
    k_combine<<<256, 256, 0, stream>>>(ws, S_E1, -1, -1, -1, -1, 0, 0, 0, 0, INVF[16], 0);
    for (int b = 3; b >= 0; b--){
        GEMM(S_T4, S_E1, S_E2, 0, 0, 1.0, 0.0, -1, 0.0);
        k_combine<<<256, 256, 0, stream>>>(ws, S_E1, S_E2, S_LAT, S_T2, S_T3,
            1.0, INVF[4*b+1], INVF[4*b+2], INVF[4*b+3], INVF[4*b], 0);
    }
    for (int r = 1; r <= 10; r++){
        int src = (r & 1) ? S_E1 : S_E2, dst = (r & 1) ? S_E2 : S_E1;
        ZG(src, src, dst, 0, 0, 1.0, 0.0, -1, 0.0, 1, r);
    }
    GEMM(S_EW, S_E1, S_M2, 1, 0, 1.0, 0.0, -1, 0.0);   // new_Ew = conj(Ew) expm(new_uw)
    k_cast_out<<<256, 256, 0, stream>>>(ws, S_M2, out, off_ew, f);

    // -------- logm(Ew): one cooperative kernel (6 DB stages + Cayley + artanh + S) ----
    {
        void* cargs[] = { (void*)&ws };
        hipLaunchCooperativeKernel((void*)k_logm_coop, dim3(256), dim3(256),
                                   cargs, 0, stream);
    }

    // -------- batched exp_tens = expm(c_u S): shared powers + pooled squaring --------
    k_norm1inf<<<1, 256, 0, stream>>>(MP(PBASE), ws, 12);   // rigorous norm bound inputs
    k_fro<<<1, 256, 0, stream>>>(MP(PBASE), ws);
    k_snorm<<<1, 1, 0, stream>>>(ws);
    k_theta_pool<<<1, 256, 0, stream>>>(ws);
    k_weights<<<1, 256, 0, stream>>>(ws);
    for (int m = 1; m < 32; m *= 2){
        int cnt = (m < 32 - m) ? m : (32 - m);
        k_zgemm<<<dim3(16,16,cnt), 256, 0, stream>>>(MP(PBASE + m - 1), MP(PBASE), MP(PBASE + m),
            nullptr, 0, 0, 1.0, 0.0, 0.0, ws, 0, 0, 0, 0, 0L, MATD, MATD);
    }
    for (int p = 0; p < P; p++){
        k_combo<<<dim3(256,16), 256, 0, stream>>>(ws, out, off_ex, f, p, K);
        for (int r = 1; r <= 12; r++)
            k_pool_sq<<<dim3(16,16,K), 256, 0, stream>>>(ws, r, p, K);
        k_pool_out<<<dim3(256,K), 256, 0, stream>>>(ws, out, off_ex, f, p, K);
    }
}

// Round 2
// 29140.182 us; speedup vs baseline: 1.5084x; 1.5084x over previous
//
#include <hip/hip_runtime.h>
#include <hip/hip_cooperative_groups.h>
#include <hip/hip_bf16.h>
#include <math.h>

namespace cg = cooperative_groups;

#define NN 65536
#define MATD 131072L   // doubles per complex matrix (re plane + im plane)
#define MAT0 32768L    // header size in doubles

// ws header offsets (doubles)
#define SC_DT 0
#define SC_NUINV 3
#define SC_EXPM_S 4
#define SC_EXPM_SCALE 5
#define SC_NORMS2 6
#define SC_MU 7
// 8,9: n1,ninf of M ; 12,13: n1,ninf of S ; 14: F^2 of S
#define W_UNIT_RE 64
#define W_UNIT_IM 320
#define W_C_RE 576
#define W_C_IM 832
#define W_LD_RE 1088
#define W_LD_IM 1344
#define W_SU 1600
#define W_SLOT 1856
#define W_SLOTU 2112        // 256 entries -> ends 2368
#define W_W 2432            // 256*33*2 doubles -> ends 19328
#define TRBASE 22528        // 96 doubles per inversion (2 per NS iter, <=48 iters)
#define NRM_ROW 30208       // 256 row-sum partials
#define NRM_COL 30464       // 256 col-sum partials
#define NRM_DEV 30720       // 256 row sums of |M - I|
#define NPOOL 256           // virtual pool capacity

// matrix slots
#define S_EW 0
#define S_NUW 1
#define S_LAT 2
#define S_T2 3
#define S_T3 4
#define S_T4 5
#define S_E1 6
#define S_E2 7
#define S_M 8
#define S_M2 9
#define S_Y 10
#define S_Y2 11
#define S_IY 12
#define S_X 13
#define S_X2 14
#define S_T 15
#define S_W 16
#define S_V 17
#define S_G 18
#define S_G2 19
#define PBASE 20            // S^k at PBASE+k-1, k=1..32 -> 20..51
#define POOL0 52            // physical pool

#define PI_D 3.14159265358979323846
#define LOG_SCALE 32.0      // 2 * 2^4 sqrt stages (2 DB + 2 NS-sqrt)

__device__ inline double ldin(const void* p, int i, int dt){
    if (dt == 0) return (double)__bfloat162float(((const __hip_bfloat16*)p)[i]);
    if (dt == 1) return (double)((const float*)p)[i];
    return ((const double*)p)[i];
}

// ---------------- init: zero header ----------------
__global__ __launch_bounds__(256) void k_init(double* ws){
    ws[blockIdx.x * 256 + threadIdx.x] = 0.0;   // grid 128 -> 32768
}

// ---------------- input dtype detection ----------------
__global__ __launch_bounds__(64) void k_detect(const void* x, double* ws){
    __shared__ int ok[3];
    int t = threadIdx.x;
    if (t < 3) ok[t] = 1;
    __syncthreads();
    const __hip_bfloat16* pb = (const __hip_bfloat16*)x;
    for (int k = t; k < 256; k += 64){
        float v = __bfloat162float(pb[k]);
        if (!(v > 0.40f && v < 1.60f)) ok[0] = 0;
    }
    const float* pf = (const float*)x;
    { float v = pf[t]; if (!(v > 0.40f && v < 1.60f)) ok[1] = 0; }
    const double* pd = (const double*)x;
    { double v = pd[t]; if (!(v > 0.40 && v < 1.60)) ok[2] = 0; }
    __syncthreads();
    if (t == 0) ws[SC_DT] = ok[0] ? 0.0 : (ok[1] ? 1.0 : 2.0);
}

// ---------------- small vector stage (1 block) ----------------
__global__ __launch_bounds__(256) void k_small(
    const void* xin, const void* Ar, const void* Ai,
    const void* cAr, const void* cAi,
    double* ws, float* out)
{
    __shared__ double xs[256], twc[256], tws[256], ur[256], ui[256], red[256];
    int t = threadIdx.x;
    int dt = (int)ws[SC_DT];
    double x = ldin(xin, t, dt);
    xs[t] = x;
    red[t] = log(x);
    double ang = -2.0 * PI_D * (double)t / 256.0;
    twc[t] = cos(ang); tws[t] = sin(ang);
    __syncthreads();
    for (int s = 128; s > 0; s >>= 1){ if (t < s) red[t] += red[t+s]; __syncthreads(); }
    double slog = red[0];
    __syncthreads();
    double dy = (t == 0) ? 0.0 : (x - xs[t-1]);
    double r = x * exp(-slog / 256.0);
    double unr = r * cos(dy), uni = r * sin(dy);
    ur[t] = unr; ui[t] = uni;
    ws[W_UNIT_RE + t] = unr; ws[W_UNIT_IM + t] = uni;
    __syncthreads();
    double fr = 0.0, fi = 0.0;
    for (int n = 0; n < 256; n++){
        int m = (t * n) & 255;
        double c = twc[m], s = tws[m];
        fr += ur[n]*c - ui[n]*s;
        fi += ur[n]*s + ui[n]*c;
    }
    red[t] = fr; __syncthreads();
    for (int s = 128; s > 0; s >>= 1){ if (t < s) red[t] += red[t+s]; __syncthreads(); }
    double sr = red[0]; __syncthreads();
    red[t] = fi; __syncthreads();
    for (int s = 128; s > 0; s >>= 1){ if (t < s) red[t] += red[t+s]; __syncthreads(); }
    double si = red[0];
    double den = sr*sr + si*si;
    double cr = (fr*sr + fi*si) / den, ci = (fi*sr - fr*si) / den;
    ws[W_C_RE + t] = cr; ws[W_C_IM + t] = ci;
    double ar = ldin(Ar, t, dt), ai = ldin(Ai, t, dt);
    double car = ldin(cAr, t, dt), cai = ldin(cAi, t, dt);
    double pr = ar*unr - ai*uni, pi = ar*uni + ai*unr;
    double qr = car*pr + cai*pi, qi = car*pi - cai*pr;
    out[t] = (float)(x + atan2(qi, qr));
    double ldr = 0.5 * log((qr*qr + qi*qi) / (unr*unr + uni*uni));
    double ldi = atan2(qi, qr) - atan2(uni, unr);
    ws[W_LD_RE + t] = ldr; ws[W_LD_IM + t] = ldi;
}

// ---------------- build Ew and new_uw (fp64 planes) ----------------
__global__ __launch_bounds__(256) void k_build_mats(
    const void* Ewr, const void* Ewi, const void* uwr, const void* uwi, double* ws)
{
    int ij = blockIdx.x * 256 + threadIdx.x;
    int i = ij >> 8, j = ij & 255;
    int dt = (int)ws[SC_DT];
    double* EW = ws + MAT0 + (size_t)S_EW * MATD;
    EW[ij] = ldin(Ewr, ij, dt); EW[NN + ij] = ldin(Ewi, ij, dt);
    double* U = ws + MAT0 + (size_t)S_NUW * MATD;
    if (i == 0){ U[ij] = ws[W_LD_RE + j]; U[NN + ij] = ws[W_LD_IM + j]; }
    else { int src = (i-1)*256 + j; U[ij] = ldin(uwr, src, dt); U[NN + ij] = ldin(uwi, src, dt); }
}

// ---------------- norms: ws[idx]=n1, ws[idx+1]=ninf ----
__global__ __launch_bounds__(256) void k_norm1inf(const double* M, double* ws, int idx)
{
    __shared__ double cs[256], rs[256];
    int t = threadIdx.x;
    double c = 0.0, r = 0.0;
    for (int i = 0; i < 256; i++){
        c += fabs(M[i*256 + t]) + fabs(M[NN + i*256 + t]);
        r += fabs(M[t*256 + i]) + fabs(M[NN + t*256 + i]);
    }
    cs[t] = c; rs[t] = r; __syncthreads();
    for (int s = 128; s > 0; s >>= 1){
        if (t < s){ cs[t] = fmax(cs[t], cs[t+s]); rs[t] = fmax(rs[t], rs[t+s]); }
        __syncthreads();
    }
    if (t == 0){
        ws[idx] = cs[0]; ws[idx+1] = rs[0];
        ws[SC_NUINV] = 1.0 / (cs[0] * rs[0]);
    }
}

// Frobenius^2 -> ws[14]
__global__ __launch_bounds__(256) void k_fro(const double* M, double* ws)
{
    __shared__ double red[256];
    int t = threadIdx.x;
    double s = 0.0;
    for (int i = 0; i < 256; i++){
        double a = M[i*256 + t], b = M[NN + i*256 + t];
        s += a*a + b*b;
    }
    red[t] = s; __syncthreads();
    for (int k = 128; k > 0; k >>= 1){ if (t < k) red[t] += red[t+k]; __syncthreads(); }
    if (t == 0) ws[14] = red[0];
}

// rigorous sigma_max upper bound: min( sqrt(n1*ninf), ||S||_F )
__global__ void k_snorm(double* ws)
{
    double b1 = sqrt(ws[12] * ws[13]);
    double b2 = sqrt(ws[14]);
    ws[SC_NORMS2] = fmin(b1, b2);
}

// ---------------- complex GEMM (host-launched; expm + powers path) ----------------
__global__ __launch_bounds__(256) void k_zgemm(
    const double* __restrict__ Ab, const double* __restrict__ Bb,
    double* __restrict__ Cb, const double* __restrict__ Db,
    int preA, int preB, double alpha, double beta, double gamma,
    double* __restrict__ ws, int fm, int round, int flagIdx, int trIdx,
    long sA, long sB, long sC)
{
    int z = blockIdx.z;
    const double* A = Ab + (size_t)z * sA;
    const double* B = Bb + (size_t)z * sB;
    double* C = Cb + (size_t)z * sC;
    int tx = threadIdx.x & 15, ty = threadIdx.x >> 4;
    int row = blockIdx.y * 16 + ty, col = blockIdx.x * 16 + tx;
    if (fm == 1 && round > (int)ws[SC_EXPM_S]){
        C[row*256 + col] = A[row*256 + col];
        C[NN + row*256 + col] = A[NN + row*256 + col];
        return;
    }
    __shared__ double Asr[16][17], Asi[16][17], Bsr[16][17], Bsi[16][17];
    double cr = 0.0, ci = 0.0;
    for (int k0 = 0; k0 < 256; k0 += 16){
        int ac = k0 + tx;
        double a_re = A[row*256 + ac], a_im = A[NN + row*256 + ac];
        if (preA == 1) a_im = -a_im;
        else if (preA == 2){ if (row == ac) a_re -= 1.0; }
        int br = k0 + ty;
        double b_re = B[br*256 + col], b_im = B[NN + br*256 + col];
        if (preB == 1){ b_re = ((br == col) ? 2.0 : 0.0) - b_re; b_im = -b_im; }
        Asr[ty][tx] = a_re; Asi[ty][tx] = a_im;
        Bsr[ty][tx] = b_re; Bsi[ty][tx] = b_im;
        __syncthreads();
        #pragma unroll
        for (int kk = 0; kk < 16; kk++){
            double xr = Asr[ty][kk], xi = Asi[ty][kk];
            double yr = Bsr[kk][tx], yi = Bsi[kk][tx];
            cr += xr*yr - xi*yi;
            ci += xr*yi + xi*yr;
        }
        __syncthreads();
    }
    double outr = alpha * cr, outi = alpha * ci;
    if (Db){ outr += beta * Db[row*256 + col]; outi += beta * Db[NN + row*256 + col]; }
    if (row == col) outr += gamma;
    C[row*256 + col] = outr;
    C[NN + row*256 + col] = outi;
}

// ---- elementwise combine (expm path) ----
__global__ __launch_bounds__(256) void k_combine(double* ws, int dst,
    int s1, int s2, int s3, int s4,
    double a1, double a2, double a3, double a4, double g, int mode)
{
    int ij = blockIdx.x * 256 + threadIdx.x;
    int i = ij >> 8, j = ij & 255;
    double f1 = 1.0, f2 = 1.0;
    if (mode == 1){ f1 = ws[SC_EXPM_SCALE]; }
    double* C = ws + MAT0 + (size_t)dst * MATD;
    double r = 0.0, m = 0.0;
    if (s1 >= 0){ const double* X = ws + MAT0 + (size_t)s1 * MATD; r += a1*f1*X[ij]; m += a1*f1*X[NN+ij]; }
    if (s2 >= 0){ const double* X = ws + MAT0 + (size_t)s2 * MATD; r += a2*f2*X[ij]; m += a2*f2*X[NN+ij]; }
    if (s3 >= 0){ const double* X = ws + MAT0 + (size_t)s3 * MATD; r += a3*X[ij]; m += a3*X[NN+ij]; }
    if (s4 >= 0){ const double* X = ws + MAT0 + (size_t)s4 * MATD; r += a4*X[ij]; m += a4*X[NN+ij]; }
    if (i == j) r += g;
    C[ij] = r; C[NN + ij] = m;
}

__global__ void k_expm_prep(double* ws)
{
    if (threadIdx.x == 0 && blockIdx.x == 0){
        double n1 = ws[8];
        int s = 0;
        if (n1 > 0.5){
            s = (int)ceil(log2(n1 / 0.5));
            if (s < 0) s = 0; if (s > 10) s = 10;
        }
        ws[SC_EXPM_S] = (double)s;
        ws[SC_EXPM_SCALE] = ldexp(1.0, -s);
    }
}

// ==================== cooperative logm kernel ====================
// 2 DB-sqrt stages (NS inversions, warm-started when ||M-I||<0.9) +
// 2 inverse-free Newton-Schulz sqrt stages + Cayley + adaptive artanh + S.
// 256 blocks x 512 threads: split-k x2 gemm, 2 waves/SIMD.
struct ShMemC {
    double Ar[2][16][17], Ai[2][16][17], Br[2][16][17], Bi[2][16][17];
    double redA[512];
    double redB[256];
};

__global__ __launch_bounds__(512, 2) void k_logm_coop(double* __restrict__ ws)
{
    cg::grid_group grid = cg::this_grid();
    __shared__ ShMemC sh;
    const int t = threadIdx.x;
    const int b = blockIdx.x;
    const int team = t >> 8, tt = t & 255;
    const int tx = tt & 15, ty = tt >> 4;
    const int bx = b & 15, by = b >> 4;
    const int row = by*16 + ty, col = bx*16 + tx;
    const int ij2 = b*512 + t;                   // 0..131071: both planes
    const int pl = ij2 >> 16;                    // 0 re, 1 im
    const int lin = ij2 & 65535;
    const int li = lin >> 8, lj = lin & 255;
    const int tr_idx = (lj << 8) + li + (pl ? NN : 0);   // transposed index
    const bool diagre = (pl == 0) && (li == lj);

    double* const MB = ws + MAT0;
    auto SL = [&](int s){ return MB + (size_t)s * MATD; };

    // grid-uniform max over a 256-entry ws array
    auto bmax = [&](int base) -> double {
        sh.redA[t] = ws[base + (t & 255)];
        __syncthreads();
        for (int s = 256; s > 0; s >>= 1){
            if (t < s) sh.redA[t] = fmax(sh.redA[t], sh.redA[t+s]);
            __syncthreads();
        }
        double r = sh.redA[0]; __syncthreads();
        return r;
    };

    // block b computes row-b and col-b abs sums (and optionally |M-I| row sum)
    auto partials = [&](const double* M, bool withDev){
        double v, dv = 0.0;
        if (t < 256){
            double e = M[b*256 + t], f = M[NN + b*256 + t];
            v = fabs(e) + fabs(f);
            if (withDev) dv = fabs(e - ((b == t) ? 1.0 : 0.0)) + fabs(f);
        } else {
            int c2 = t - 256;
            v = fabs(M[c2*256 + b]) + fabs(M[NN + c2*256 + b]);
        }
        sh.redA[t] = v;
        if (t < 256) sh.redB[t] = dv;
        __syncthreads();
        for (int s = 128; s > 0; s >>= 1){
            if (t < s){ sh.redA[t] += sh.redA[t+s]; sh.redB[t] += sh.redB[t+s]; }
            else if (t >= 256 && t < 256 + s){ sh.redA[t] += sh.redA[t+s]; }
            __syncthreads();
        }
        if (t == 0){ ws[NRM_ROW + b] = sh.redA[0]; if (withDev) ws[NRM_DEV + b] = sh.redB[0]; }
        if (t == 256){ ws[NRM_COL + b] = sh.redA[256]; }
        __syncthreads();
    };

    // C = alpha*preA(A)*preB(B) + gamma*I ; split-k x2 across teams.
    // preA: 0 none, 1 conj, 2 (A-I), 3 (3I-A). preB: 0 none, 1 (2I-B), 2 (3I-B).
    auto gemm = [&](const double* A, const double* B, double* C,
                    int preA, int preB, double alpha, double gamma, double* tr){
        double cr = 0.0, ci = 0.0;
        for (int s = 0; s < 8; s++){
            int kb = (team << 7) + (s << 4);
            int ac = kb + tx;
            double a_re = A[row*256 + ac], a_im = A[NN + row*256 + ac];
            if (preA == 1) a_im = -a_im;
            else if (preA == 2){ if (row == ac) a_re -= 1.0; }
            else if (preA == 3){ a_re = ((row == ac) ? 3.0 : 0.0) - a_re; a_im = -a_im; }
            int br = kb + ty;
            double b_re = B[br*256 + col], b_im = B[NN + br*256 + col];
            if (preB == 1){ b_re = ((br == col) ? 2.0 : 0.0) - b_re; b_im = -b_im; }
            else if (preB == 2){ b_re = ((br == col) ? 3.0 : 0.0) - b_re; b_im = -b_im; }
            sh.Ar[team][ty][tx] = a_re; sh.Ai[team][ty][tx] = a_im;
            sh.Br[team][ty][tx] = b_re; sh.Bi[team][ty][tx] = b_im;
            __syncthreads();
            #pragma unroll
            for (int kk = 0; kk < 16; kk++){
                double xr = sh.Ar[team][ty][kk], xi = sh.Ai[team][ty][kk];
                double yr = sh.Br[team][kk][tx], yi = sh.Bi[team][kk][tx];
                cr += xr*yr - xi*yi;
                ci += xr*yi + xi*yr;
            }
            __syncthreads();
        }
        if (team == 1){ sh.Ar[1][ty][tx] = cr; sh.Ai[1][ty][tx] = ci; }
        __syncthreads();
        if (team == 0){
            cr += sh.Ar[1][ty][tx]; ci += sh.Ai[1][ty][tx];
            cr *= alpha; ci *= alpha;
            if (row == col) cr += gamma;
            C[row*256 + col] = cr;
            C[NN + row*256 + col] = ci;
            if (tr && row == col){ atomicAdd(tr, cr); atomicAdd(tr + 1, ci); }
        }
        __syncthreads();
    };

    double* dMm = SL(S_M);  double* dM2 = SL(S_M2);
    double* dYy = SL(S_Y);  double* dY2 = SL(S_Y2);
    double* dX  = SL(S_X);  double* dX2 = SL(S_X2);
    double* dT  = SL(S_T);
    double* dG  = SL(S_G);  double* dG2 = SL(S_G2);
    double* dW  = SL(S_W);  double* dV  = SL(S_V);
    double* dLT = SL(S_LAT);
    double* dS  = SL(PBASE);

    int invid = 0;
    // NS inverse of src. Requires NRM_ROW/COL (norms of src) synced.
    // dev = ||src - I||inf (warm start when < 0.9). Returns buffer with inverse.
    auto inv = [&](const double* src, double dev, int maxit,
                   double& n1, double& ninf) -> double* {
        n1 = bmax(NRM_COL); ninf = bmax(NRM_ROW);
        if (dev < 0.9){
            double v = -src[ij2];
            if (diagre) v += 2.0;
            dX[ij2] = v;                         // X0 = 2I - src (resid dev^2)
        } else {
            double nu = 1.0 / (n1 * ninf);
            double v = src[tr_idx] * nu;
            dX[ij2] = pl ? -v : v;               // X0 = conj(src)^T * nu
        }
        grid.sync();
        double* xc = dX; double* xo = dX2;
        for (int i2 = 0; i2 < maxit; i2++){
            double* tr = ws + (TRBASE + invid*96 + 2*i2);  // pre-zeroed
            gemm(src, xc, dT, 0, 0, 1.0, 0.0, tr);         // T = M X (+trace)
            grid.sync();
            double resid = fabs(256.0 - tr[0]) + fabs(tr[1]);
            if (resid < 2.56e-8) break;
            gemm(xc, dT, xo, 0, 1, 1.0, 0.0, nullptr);     // X' = X (2I - T)
            grid.sync();
            double* tm = xc; xc = xo; xo = tm;
        }
        invid++;
        return xc;
    };

    double* bcur = SL(S_EW);

    // ---- 2 scaled product-form DB sqrt stages (handle full spectrum) ----
    for (int st = 0; st < 2; st++){
        dMm[ij2] = bcur[ij2];
        dYy[ij2] = bcur[ij2];
        partials(bcur, true);
        grid.sync();
        double* mc = dMm; double* mo = dM2; double* yc = dYy; double* yo = dY2;
        double dev = bmax(NRM_DEV);
        for (int it = 0; it < 24; it++){
            if (dev < 1e-9) break;
            double nm1, nminf;
            double* iy = inv(mc, dev, 48, nm1, nminf);
            partials(iy, false);
            grid.sync();
            double ni1 = bmax(NRM_COL), niinf = bmax(NRM_ROW);
            double mu = pow((ni1 * niinf) / (nm1 * nminf), 0.125);
            if (!(mu > 0.125)) mu = 0.125;
            if (mu > 8.0) mu = 8.0;
            double mu2 = mu*mu, rmu = 1.0/mu, rmu2 = rmu*rmu;
            gemm(yc, iy, dG, 0, 0, 1.0, 0.0, nullptr);     // G = Y * M^-1
            {   // M' = 0.25*(mu^2 M + mu^-2 M^-1) + 0.5 I
                double r = 0.25 * (mu2 * mc[ij2] + rmu2 * iy[ij2]);
                if (diagre) r += 0.5;
                mo[ij2] = r;
            }
            grid.sync();
            yo[ij2] = 0.5 * (mu * yc[ij2] + rmu * dG[ij2]); // Y' = 0.5(mu Y + G/mu)
            partials(mo, true);
            grid.sync();
            dev = bmax(NRM_DEV);
            double* tm = mc; mc = mo; mo = tm;
            tm = yc; yc = yo; yo = tm;
        }
        bcur = yc;
    }

    // ---- 2 inverse-free Newton-Schulz sqrt stages ----
    // input spectrum has |arg| < pi/4 -> rho(I - B/c) < 1 guaranteed for
    // c = sqrt(n1*ninf) >= sigma_max.
    for (int st = 0; st < 2; st++){
        partials(bcur, false);
        grid.sync();
        double c = sqrt(bmax(NRM_COL) * bmax(NRM_ROW));
        double invc = 1.0 / c, sc = sqrt(c);
        dYy[ij2] = bcur[ij2] * invc;                       // Y0 = B/c
        dX[ij2]  = diagre ? 1.0 : 0.0;                     // Z0 = I
        grid.sync();
        double* Ycur = dYy; double* Yalt = dY2;
        double* Zcur = dX;  double* Zalt = dX2;
        for (int it = 0; it < 30; it++){
            gemm(Zcur, Ycur, dT, 0, 0, 1.0, 0.0, nullptr); // E = Z Y
            grid.sync();
            partials(dT, true);                            // ||E - I||inf
            grid.sync();
            double dv = bmax(NRM_DEV);
            if (dv < 1e-11) break;
            gemm(Ycur, dT, Yalt, 0, 2, 0.5, 0.0, nullptr); // Y' = 0.5 Y (3I - E)
            gemm(dT, Zcur, Zalt, 3, 0, 0.5, 0.0, nullptr); // Z' = 0.5 (3I - E) Z
            grid.sync();
            double* tm = Ycur; Ycur = Yalt; Yalt = tm;
            tm = Zcur; Zcur = Zalt; Zalt = tm;
        }
        dMm[ij2] = sc * Ycur[ij2];                         // B_{s+1} = sqrt(c) Y
        grid.sync();
        bcur = dMm;
    }

    // ---- Cayley: W = (B - I)(B + I)^-1 ----
    dG[ij2] = bcur[ij2] + (diagre ? 1.0 : 0.0);            // G = B + I
    grid.sync();
    partials(dG, true);
    grid.sync();
    double devG = bmax(NRM_DEV);
    double cn1, cninf;
    double* giy = inv(dG, devG, 48, cn1, cninf);
    gemm(bcur, giy, dW, 2, 0, 1.0, 0.0, nullptr);          // W = (B-I)(B+I)^-1
    grid.sync();
    gemm(dW, dW, dV, 0, 0, 1.0, 0.0, nullptr);             // V = W^2
    partials(dW, false);                                   // ||W||inf for degree
    grid.sync();
    double nW = bmax(NRM_ROW);
    // adaptive odd-series degree: tail <= q^{J+1}/(1-q), q = ||V|| <= nW^2
    double q = nW * nW;
    int J = 19;
    if (q < 0.5){
        J = 1;
        double qp = q * q;     // q^{J+1}
        while (J < 19 && qp >= 1e-16 * (1.0 - q)){ qp *= q; J++; }
    }
    dG[ij2] = diagre ? 1.0/(double)(2*J + 1) : 0.0;        // Horner seed
    grid.sync();
    double* gc = dG; double* go = dG2;
    for (int j = J - 1; j >= 0; j--){
        gemm(dV, gc, go, 0, 0, 1.0, 1.0/(double)(2*j + 1), nullptr);
        grid.sync();
        double* tm = gc; gc = go; go = tm;
    }
    gemm(dW, gc, dLT, 0, 0, 1.0, 0.0, nullptr);            // LAT = artanh(W)
    grid.sync();
    // S = LOG_SCALE * conj(LAT - LAT^T)
    {
        double vv = dLT[ij2] - dLT[tr_idx];
        dS[ij2] = pl ? -LOG_SCALE * vv : LOG_SCALE * vv;
    }
}

// theta per u (rigorous upper bound); theta>4 -> scaling+squaring pool
__global__ __launch_bounds__(256) void k_theta_pool(double* ws)
{
    __shared__ double th[256]; __shared__ int rk[256];
    int t = threadIdx.x;
    double nS = ws[SC_NORMS2];
    double cr = ws[W_C_RE + t], ci = ws[W_C_IM + t];
    th[t] = sqrt(cr*cr + ci*ci) * nS;
    __syncthreads();
    int r = 0;
    for (int v = 0; v < 256; v++){
        if (th[v] > th[t] || (th[v] == th[t] && v < t)) r++;
    }
    rk[t] = r;
    __syncthreads();
    if (t == 0){
        int cnt = 0;
        for (int u = 0; u < 256; u++){
            double s = 0.0; int slot = -1;
            if (th[u] > 4.0 && rk[u] < NPOOL){
                double e = ceil(log2(th[u] / 4.0));
                if (e < 1.0) e = 1.0; if (e > 12.0) e = 12.0;
                s = e; slot = cnt;
                ws[W_SLOTU + cnt] = (double)u;
                cnt++;
            }
            ws[W_SU + u] = s;
            ws[W_SLOT + u] = (double)slot;
        }
        for (int k = cnt; k < NPOOL; k++) ws[W_SLOTU + k] = -1.0;
    }
}

// weights w[u][k] = (c_u / 2^{s_u})^k / k!
__global__ __launch_bounds__(256) void k_weights(double* ws)
{
    int u = threadIdx.x;
    double sc = ldexp(1.0, -(int)ws[W_SU + u]);
    double cr = ws[W_C_RE + u] * sc, ci = ws[W_C_IM + u] * sc;
    double wr = 1.0, wi = 0.0;
    ws[W_W + (u*33)*2] = 1.0; ws[W_W + (u*33)*2 + 1] = 0.0;
    for (int k = 1; k <= 32; k++){
        double inv = 1.0 / (double)k;
        double nr = (wr*cr - wi*ci) * inv, ni = (wr*ci + wi*cr) * inv;
        wr = nr; wi = ni;
        ws[W_W + (u*33 + k)*2] = wr;
        ws[W_W + (u*33 + k)*2 + 1] = wi;
    }
}

// exp_tens[u] = sum_k w[u][k] S^k -> f32 out (non-pooled) or fp64 pool base
__global__ __launch_bounds__(256) void k_combo(double* ws, float* out, long off_ex, int f,
                                               int pass, int K)
{
    __shared__ double wre[16][33], wim[16][33];
    __shared__ int anywork;
    int t = threadIdx.x;
    int row = blockIdx.x, ug = blockIdx.y;
    if (t == 0) anywork = (pass == 0) ? 1 : 0;
    __syncthreads();
    if (pass > 0 && t < 16){
        int u = ug*16 + t;
        int slot = (int)ws[W_SLOT + u];
        int phys = slot - pass * K;
        if (slot >= 0 && phys >= 0 && phys < K) anywork = 1;
    }
    __syncthreads();
    if (!anywork) return;
    for (int i = t; i < 16*33; i += 256){
        int g = i / 33, k = i % 33;
        int u = ug*16 + g;
        wre[g][k] = ws[W_W + (u*33 + k)*2];
        wim[g][k] = ws[W_W + (u*33 + k)*2 + 1];
    }
    __syncthreads();
    int j = t, ij = row*256 + j;
    double ar[16], ai[16];
    #pragma unroll
    for (int g = 0; g < 16; g++){
        ar[g] = (row == j) ? wre[g][0] : 0.0;
        ai[g] = (row == j) ? wim[g][0] : 0.0;
    }
    for (int k = 1; k <= 32; k++){
        const double* SP = ws + MAT0 + (size_t)(PBASE + k - 1) * MATD;
        double sre = SP[ij], sim = SP[NN + ij];
        #pragma unroll
        for (int g = 0; g < 16; g++){
            ar[g] += wre[g][k]*sre - wim[g][k]*sim;
            ai[g] += wre[g][k]*sim + wim[g][k]*sre;
        }
    }
    for (int g = 0; g < 16; g++){
        int u = ug*16 + g;
        int slot = (int)ws[W_SLOT + u];
        if (slot >= 0){
            int phys = slot - pass * K;
            if (phys >= 0 && phys < K){
                double* P = ws + MAT0 + (size_t)(POOL0 + phys) * MATD;
                P[ij] = ar[g]; P[NN + ij] = ai[g];
            }
        } else if (pass == 0){
            long base = off_ex + (long)u * NN * f + (long)ij * f;
            out[base] = (float)ar[g];
            if (f == 2) out[base + 1] = (float)ai[g];
        }
    }
}

// pool squaring
__global__ __launch_bounds__(256) void k_pool_sq(double* ws, int round, int pass, int K)
{
    int z = blockIdx.z;
    int vs = pass * K + z;
    int u = (vs < NPOOL) ? (int)ws[W_SLOTU + vs] : -1;
    if (u < 0) return;
    if (round > (int)ws[W_SU + u]) return;
    const double* A = ws + MAT0 + (size_t)(POOL0 + ((round & 1) ? 0 : K) + z) * MATD;
    double* C = ws + MAT0 + (size_t)(POOL0 + ((round & 1) ? K : 0) + z) * MATD;
    int tx = threadIdx.x & 15, ty = threadIdx.x >> 4;
    int row = blockIdx.y*16 + ty, col = blockIdx.x*16 + tx;
    __shared__ double Asr[16][17], Asi[16][17], Bsr[16][17], Bsi[16][17];
    double cr = 0.0, ci = 0.0;
    for (int k0 = 0; k0 < 256; k0 += 16){
        Asr[ty][tx] = A[row*256 + k0 + tx];
        Asi[ty][tx] = A[NN + row*256 + k0 + tx];
        Bsr[ty][tx] = A[(k0 + ty)*256 + col];
        Bsi[ty][tx] = A[NN + (k0 + ty)*256 + col];
        __syncthreads();
        #pragma unroll
        for (int kk = 0; kk < 16; kk++){
            double xr = Asr[ty][kk], xi = Asi[ty][kk];
            double yr = Bsr[kk][tx], yi = Bsi[kk][tx];
            cr += xr*yr - xi*yi;
            ci += xr*yi + xi*yr;
        }
        __syncthreads();
    }
    C[row*256 + col] = cr;
    C[NN + row*256 + col] = ci;
}

__global__ __launch_bounds__(256) void k_pool_out(const double* ws, float* out, long off_ex,
                                                  int f, int pass, int K)
{
    int z = blockIdx.y;
    int vs = pass * K + z;
    int u = (vs < NPOOL) ? (int)ws[W_SLOTU + vs] : -1;
    if (u < 0) return;
    int su = (int)ws[W_SU + u];
    int ij = blockIdx.x * 256 + threadIdx.x;
    const double* P = ws + MAT0 + (size_t)(POOL0 + ((su & 1) ? K : 0) + z) * MATD;
    long base = off_ex + (long)u * NN * f + (long)ij * f;
    out[base] = (float)P[ij];
    if (f == 2) out[base + 1] = (float)P[NN + ij];
}

__global__ __launch_bounds__(256) void k_cast_out(const double* ws, int slot, float* out, long off, int f)
{
    int ij = blockIdx.x * 256 + threadIdx.x;
    const double* P = ws + MAT0 + (size_t)slot * MATD;
    out[off + (long)ij * f] = (float)P[ij];
    if (f == 2) out[off + (long)ij * f + 1] = (float)P[NN + ij];
}

// ============================ host ============================
extern "C" void kernel_launch(void* const* d_in, const int* in_sizes, int n_in,
                              void* d_out, int out_size, void* d_ws, size_t ws_size,
                              hipStream_t stream)
{
    double* ws = (double*)d_ws;
    float* out = (float*)d_out;

    int f = (out_size >= 33816832) ? 2 : 1;
    long off_ex = 256;
    long off_uw = off_ex + (long)f * 16777216L;
    long off_ew = off_uw + (long)f * 65536L;

    k_init<<<128, 256, 0, stream>>>(ws);
    k_detect<<<1, 64, 0, stream>>>(d_in[0], ws);
    k_small<<<1, 256, 0, stream>>>(d_in[0], d_in[1], d_in[2], d_in[3], d_in[4], ws, out);

    long slotsAvail = (long)(ws_size / 8 - MAT0) / MATD;
    if (slotsAvail < POOL0 + 32) return;
    int K = (int)((slotsAvail - POOL0) / 2);
    if (K > NPOOL) K = NPOOL;
    if (K < 16) K = 16;
    int P = (NPOOL + K - 1) / K;

    auto MP = [&](int s){ return ws + MAT0 + (size_t)s * MATD; };
    auto ZG = [&](int a, int b, int c, int preA, int preB, double al, double be,
                  int d, double ga, int fm, int round){
        k_zgemm<<<dim3(16,16,1), 256, 0, stream>>>(MP(a), MP(b), MP(c),
            d >= 0 ? MP(d) : nullptr, preA, preB, al, be, ga, ws,
            fm, round, 0, 0, 0L, 0L, 0L);
    };
    auto GEMM = [&](int a, int b, int c, int preA, int preB, double al, double be, int d, double ga){
        ZG(a, b, c, preA, preB, al, be, d, ga, 0, 0);
    };

    k_build_mats<<<256, 256, 0, stream>>>(d_in[5], d_in[6], d_in[7], d_in[8], ws);
    k_cast_out<<<256, 256, 0, stream>>>(ws, S_NUW, out, off_uw, f);

    // -------- expm(new_uw): scaling + Paterson-Stockmeyer deg-16 Taylor + squarings ----
    static const double INVF[17] = {
        1.0, 1.0, 0.5, 1.0/6.0, 1.0/24.0, 1.0/120.0, 1.0/720.0, 1.0/5040.0,
        1.0/40320.0, 1.0/362880.0, 1.0/3628800.0, 1.0/39916800.0, 1.0/479001600.0,
        1.0/6227020800.0, 1.0/87178291200.0, 1.0/1307674368000.0, 1.0/20922789888000.0 };
    k_norm1inf<<<1, 256, 0, stream>>>(MP(S_NUW), ws, 8);
    k_expm_prep<<<1, 64, 0, stream>>>(ws);
    k_combine<<<256, 256, 0, stream>>>(ws, S_LAT, S_NUW, -1, -1, -1, 1.0, 0, 0, 0, 0.0, 1);
    GEMM(S_LAT, S_LAT, S_T2, 0, 0, 1.0, 0.0, -1, 0.0);
    GEMM(S_T2, S_LAT, S_T3, 0, 0, 1.0, 0.0, -1, 0.0);
    GEMM(S_T2, S_T2, S_T4, 0, 0, 1.0, 0.0, -1, 0.0);
    k_combine<<<256, 256, 0, stream>>>(ws, S_E1, -1, -1, -1, -1, 0, 0, 0, 0, INVF[16], 0);
    for (int b = 3; b >= 0; b--){
        GEMM(S_T4, S_E1, S_E2, 0, 0, 1.0, 0.0, -1, 0.0);
        k_combine<<<256, 256, 0, stream>>>(ws, S_E1, S_E2, S_LAT, S_T2, S_T3,
            1.0, INVF[4*b+1], INVF[4*b+2], INVF[4*b+3], INVF[4*b], 0);
    }
    for (int r = 1; r <= 10; r++){
        int src = (r & 1) ? S_E1 : S_E2, dst = (r & 1) ? S_E2 : S_E1;
        ZG(src, src, dst, 0, 0, 1.0, 0.0, -1, 0.0, 1, r);
    }
    GEMM(S_EW, S_E1, S_M2, 1, 0, 1.0, 0.0, -1, 0.0);   // new_Ew = conj(Ew) expm(new_uw)
    k_cast_out<<<256, 256, 0, stream>>>(ws, S_M2, out, off_ew, f);

    // -------- logm(Ew): one cooperative kernel --------
    {
        void* cargs[] = { (void*)&ws };
        hipLaunchCooperativeKernel((void*)k_logm_coop, dim3(256), dim3(512),
                                   cargs, 0, stream);
    }

    // -------- batched exp_tens = expm(c_u S): shared powers + pooled squaring --------
    k_norm1inf<<<1, 256, 0, stream>>>(MP(PBASE), ws, 12);
    k_fro<<<1, 256, 0, stream>>>(MP(PBASE), ws);
    k_snorm<<<1, 1, 0, stream>>>(ws);
    k_theta_pool<<<1, 256, 0, stream>>>(ws);
    k_weights<<<1, 256, 0, stream>>>(ws);
    for (int m = 1; m < 32; m *= 2){
        int cnt = (m < 32 - m) ? m : (32 - m);
        k_zgemm<<<dim3(16,16,cnt), 256, 0, stream>>>(MP(PBASE + m - 1), MP(PBASE), MP(PBASE + m),
            nullptr, 0, 0, 1.0, 0.0, 0.0, ws, 0, 0, 0, 0, 0L, MATD, MATD);
    }
    for (int p = 0; p < P; p++){
        k_combo<<<dim3(256,16), 256, 0, stream>>>(ws, out, off_ex, f, p, K);
        for (int r = 1; r <= 12; r++)
            k_pool_sq<<<dim3(16,16,K), 256, 0, stream>>>(ws, r, p, K);
        k_pool_out<<<dim3(256,K), 256, 0, stream>>>(ws, out, off_ex, f, p, K);
    }
}

// Round 3
// 23676.836 us; speedup vs baseline: 1.8565x; 1.2307x over previous
//
#include <hip/hip_runtime.h>
#include <hip/hip_bf16.h>
#include <math.h>

#define NN 65536
#define MATD 131072L   // doubles per complex matrix (re plane + im plane)
#define MAT0 32768L    // header size in doubles

// ws header offsets (doubles)
#define SC_DT 0
#define SC_NUINV 3
#define SC_EXPM_S 4
#define SC_EXPM_SCALE 5
#define SC_NORMS2 6
#define SC_MU 7
// 8,9: n1,ninf of M ; 12,13: n1,ninf of S ; 14: F^2 of S
#define BARBASE 16          // 2 uint32 in ws[16] (count, generation) - zeroed by k_init
#define W_UNIT_RE 64
#define W_UNIT_IM 320
#define W_C_RE 576
#define W_C_IM 832
#define W_LD_RE 1088
#define W_LD_IM 1344
#define W_SU 1600
#define W_SLOT 1856
#define W_SLOTU 2112        // 256 entries -> ends 2368
#define W_W 2432            // 256*33*2 doubles -> ends 19328
#define TRBASE 22528        // 96 doubles per inversion (2 per NS iter, <=48 iters)
#define NRM_ROW 30208       // 256 row-sum partials
#define NRM_COL 30464       // 256 col-sum partials
#define NRM_DEV 30720       // 256 row sums of |M - I|
#define NPOOL 256           // virtual pool capacity

// matrix slots
#define S_EW 0
#define S_NUW 1
#define S_LAT 2
#define S_T2 3
#define S_T3 4
#define S_T4 5
#define S_E1 6
#define S_E2 7
#define S_M 8
#define S_M2 9
#define S_Y 10
#define S_Y2 11
#define S_IY 12
#define S_X 13
#define S_X2 14
#define S_T 15
#define S_W 16
#define S_V 17
#define S_G 18
#define S_G2 19
#define PBASE 20            // S^k at PBASE+k-1, k=1..32 -> 20..51
#define POOL0 52            // physical pool

#define PI_D 3.14159265358979323846
#define LOG_SCALE 32.0      // 2 * 2^4 sqrt stages (2 DB + 2 NS-sqrt)

__device__ inline double ldin(const void* p, int i, int dt){
    if (dt == 0) return (double)__bfloat162float(((const __hip_bfloat16*)p)[i]);
    if (dt == 1) return (double)((const float*)p)[i];
    return ((const double*)p)[i];
}

// ---- lean grid barrier: 1 atomic per block, sense-reversing generation ----
// bar[0]=arrive count, bar[1]=generation. Release on arrive (ACQ_REL add),
// acquire on exit (spin load / the add itself for last arriver).
__device__ inline void gbar(unsigned int* bar, unsigned int& gen){
    __syncthreads();
    if (threadIdx.x == 0){
        unsigned int g = gen;
        unsigned int a = __hip_atomic_fetch_add(&bar[0], 1u, __ATOMIC_ACQ_REL,
                                                __HIP_MEMORY_SCOPE_AGENT);
        if (a == 255u){
            __hip_atomic_store(&bar[0], 0u, __ATOMIC_RELAXED, __HIP_MEMORY_SCOPE_AGENT);
            __hip_atomic_store(&bar[1], g + 1u, __ATOMIC_RELEASE, __HIP_MEMORY_SCOPE_AGENT);
        } else {
            while (__hip_atomic_load(&bar[1], __ATOMIC_ACQUIRE,
                                     __HIP_MEMORY_SCOPE_AGENT) == g){
                __builtin_amdgcn_s_sleep(1);
            }
        }
    }
    __syncthreads();
    gen++;
}

// ---------------- init: zero header ----------------
__global__ __launch_bounds__(256) void k_init(double* ws){
    ws[blockIdx.x * 256 + threadIdx.x] = 0.0;   // grid 128 -> 32768
}

// ---------------- input dtype detection ----------------
__global__ __launch_bounds__(64) void k_detect(const void* x, double* ws){
    __shared__ int ok[3];
    int t = threadIdx.x;
    if (t < 3) ok[t] = 1;
    __syncthreads();
    const __hip_bfloat16* pb = (const __hip_bfloat16*)x;
    for (int k = t; k < 256; k += 64){
        float v = __bfloat162float(pb[k]);
        if (!(v > 0.40f && v < 1.60f)) ok[0] = 0;
    }
    const float* pf = (const float*)x;
    { float v = pf[t]; if (!(v > 0.40f && v < 1.60f)) ok[1] = 0; }
    const double* pd = (const double*)x;
    { double v = pd[t]; if (!(v > 0.40 && v < 1.60)) ok[2] = 0; }
    __syncthreads();
    if (t == 0) ws[SC_DT] = ok[0] ? 0.0 : (ok[1] ? 1.0 : 2.0);
}

// ---------------- small vector stage (1 block) ----------------
__global__ __launch_bounds__(256) void k_small(
    const void* xin, const void* Ar, const void* Ai,
    const void* cAr, const void* cAi,
    double* ws, float* out)
{
    __shared__ double xs[256], twc[256], tws[256], ur[256], ui[256], red[256];
    int t = threadIdx.x;
    int dt = (int)ws[SC_DT];
    double x = ldin(xin, t, dt);
    xs[t] = x;
    red[t] = log(x);
    double ang = -2.0 * PI_D * (double)t / 256.0;
    twc[t] = cos(ang); tws[t] = sin(ang);
    __syncthreads();
    for (int s = 128; s > 0; s >>= 1){ if (t < s) red[t] += red[t+s]; __syncthreads(); }
    double slog = red[0];
    __syncthreads();
    double dy = (t == 0) ? 0.0 : (x - xs[t-1]);
    double r = x * exp(-slog / 256.0);
    double unr = r * cos(dy), uni = r * sin(dy);
    ur[t] = unr; ui[t] = uni;
    ws[W_UNIT_RE + t] = unr; ws[W_UNIT_IM + t] = uni;
    __syncthreads();
    double fr = 0.0, fi = 0.0;
    for (int n = 0; n < 256; n++){
        int m = (t * n) & 255;
        double c = twc[m], s = tws[m];
        fr += ur[n]*c - ui[n]*s;
        fi += ur[n]*s + ui[n]*c;
    }
    red[t] = fr; __syncthreads();
    for (int s = 128; s > 0; s >>= 1){ if (t < s) red[t] += red[t+s]; __syncthreads(); }
    double sr = red[0]; __syncthreads();
    red[t] = fi; __syncthreads();
    for (int s = 128; s > 0; s >>= 1){ if (t < s) red[t] += red[t+s]; __syncthreads(); }
    double si = red[0];
    double den = sr*sr + si*si;
    double cr = (fr*sr + fi*si) / den, ci = (fi*sr - fr*si) / den;
    ws[W_C_RE + t] = cr; ws[W_C_IM + t] = ci;
    double ar = ldin(Ar, t, dt), ai = ldin(Ai, t, dt);
    double car = ldin(cAr, t, dt), cai = ldin(cAi, t, dt);
    double pr = ar*unr - ai*uni, pi = ar*uni + ai*unr;
    double qr = car*pr + cai*pi, qi = car*pi - cai*pr;
    out[t] = (float)(x + atan2(qi, qr));
    double ldr = 0.5 * log((qr*qr + qi*qi) / (unr*unr + uni*uni));
    double ldi = atan2(qi, qr) - atan2(uni, unr);
    ws[W_LD_RE + t] = ldr; ws[W_LD_IM + t] = ldi;
}

// ---------------- build Ew and new_uw (fp64 planes) ----------------
__global__ __launch_bounds__(256) void k_build_mats(
    const void* Ewr, const void* Ewi, const void* uwr, const void* uwi, double* ws)
{
    int ij = blockIdx.x * 256 + threadIdx.x;
    int i = ij >> 8, j = ij & 255;
    int dt = (int)ws[SC_DT];
    double* EW = ws + MAT0 + (size_t)S_EW * MATD;
    EW[ij] = ldin(Ewr, ij, dt); EW[NN + ij] = ldin(Ewi, ij, dt);
    double* U = ws + MAT0 + (size_t)S_NUW * MATD;
    if (i == 0){ U[ij] = ws[W_LD_RE + j]; U[NN + ij] = ws[W_LD_IM + j]; }
    else { int src = (i-1)*256 + j; U[ij] = ldin(uwr, src, dt); U[NN + ij] = ldin(uwi, src, dt); }
}

// ---------------- norms: ws[idx]=n1, ws[idx+1]=ninf ----
__global__ __launch_bounds__(256) void k_norm1inf(const double* M, double* ws, int idx)
{
    __shared__ double cs[256], rs[256];
    int t = threadIdx.x;
    double c = 0.0, r = 0.0;
    for (int i = 0; i < 256; i++){
        c += fabs(M[i*256 + t]) + fabs(M[NN + i*256 + t]);
        r += fabs(M[t*256 + i]) + fabs(M[NN + t*256 + i]);
    }
    cs[t] = c; rs[t] = r; __syncthreads();
    for (int s = 128; s > 0; s >>= 1){
        if (t < s){ cs[t] = fmax(cs[t], cs[t+s]); rs[t] = fmax(rs[t], rs[t+s]); }
        __syncthreads();
    }
    if (t == 0){
        ws[idx] = cs[0]; ws[idx+1] = rs[0];
        ws[SC_NUINV] = 1.0 / (cs[0] * rs[0]);
    }
}

// Frobenius^2 -> ws[14]
__global__ __launch_bounds__(256) void k_fro(const double* M, double* ws)
{
    __shared__ double red[256];
    int t = threadIdx.x;
    double s = 0.0;
    for (int i = 0; i < 256; i++){
        double a = M[i*256 + t], b = M[NN + i*256 + t];
        s += a*a + b*b;
    }
    red[t] = s; __syncthreads();
    for (int k = 128; k > 0; k >>= 1){ if (t < k) red[t] += red[t+k]; __syncthreads(); }
    if (t == 0) ws[14] = red[0];
}

// rigorous sigma_max upper bound: min( sqrt(n1*ninf), ||S||_F )
__global__ void k_snorm(double* ws)
{
    double b1 = sqrt(ws[12] * ws[13]);
    double b2 = sqrt(ws[14]);
    ws[SC_NORMS2] = fmin(b1, b2);
}

// ---------------- complex GEMM (host-launched; expm + powers path) ----------------
__global__ __launch_bounds__(256) void k_zgemm(
    const double* __restrict__ Ab, const double* __restrict__ Bb,
    double* __restrict__ Cb, const double* __restrict__ Db,
    int preA, int preB, double alpha, double beta, double gamma,
    double* __restrict__ ws, int fm, int round, int flagIdx, int trIdx,
    long sA, long sB, long sC)
{
    int z = blockIdx.z;
    const double* A = Ab + (size_t)z * sA;
    const double* B = Bb + (size_t)z * sB;
    double* C = Cb + (size_t)z * sC;
    int tx = threadIdx.x & 15, ty = threadIdx.x >> 4;
    int row = blockIdx.y * 16 + ty, col = blockIdx.x * 16 + tx;
    if (fm == 1 && round > (int)ws[SC_EXPM_S]){
        C[row*256 + col] = A[row*256 + col];
        C[NN + row*256 + col] = A[NN + row*256 + col];
        return;
    }
    __shared__ double Asr[16][17], Asi[16][17], Bsr[16][17], Bsi[16][17];
    double cr = 0.0, ci = 0.0;
    for (int k0 = 0; k0 < 256; k0 += 16){
        int ac = k0 + tx;
        double a_re = A[row*256 + ac], a_im = A[NN + row*256 + ac];
        if (preA == 1) a_im = -a_im;
        else if (preA == 2){ if (row == ac) a_re -= 1.0; }
        int br = k0 + ty;
        double b_re = B[br*256 + col], b_im = B[NN + br*256 + col];
        if (preB == 1){ b_re = ((br == col) ? 2.0 : 0.0) - b_re; b_im = -b_im; }
        Asr[ty][tx] = a_re; Asi[ty][tx] = a_im;
        Bsr[ty][tx] = b_re; Bsi[ty][tx] = b_im;
        __syncthreads();
        #pragma unroll
        for (int kk = 0; kk < 16; kk++){
            double xr = Asr[ty][kk], xi = Asi[ty][kk];
            double yr = Bsr[kk][tx], yi = Bsi[kk][tx];
            cr += xr*yr - xi*yi;
            ci += xr*yi + xi*yr;
        }
        __syncthreads();
    }
    double outr = alpha * cr, outi = alpha * ci;
    if (Db){ outr += beta * Db[row*256 + col]; outi += beta * Db[NN + row*256 + col]; }
    if (row == col) outr += gamma;
    C[row*256 + col] = outr;
    C[NN + row*256 + col] = outi;
}

// ---- elementwise combine (expm path) ----
__global__ __launch_bounds__(256) void k_combine(double* ws, int dst,
    int s1, int s2, int s3, int s4,
    double a1, double a2, double a3, double a4, double g, int mode)
{
    int ij = blockIdx.x * 256 + threadIdx.x;
    int i = ij >> 8, j = ij & 255;
    double f1 = 1.0, f2 = 1.0;
    if (mode == 1){ f1 = ws[SC_EXPM_SCALE]; }
    double* C = ws + MAT0 + (size_t)dst * MATD;
    double r = 0.0, m = 0.0;
    if (s1 >= 0){ const double* X = ws + MAT0 + (size_t)s1 * MATD; r += a1*f1*X[ij]; m += a1*f1*X[NN+ij]; }
    if (s2 >= 0){ const double* X = ws + MAT0 + (size_t)s2 * MATD; r += a2*f2*X[ij]; m += a2*f2*X[NN+ij]; }
    if (s3 >= 0){ const double* X = ws + MAT0 + (size_t)s3 * MATD; r += a3*X[ij]; m += a3*X[NN+ij]; }
    if (s4 >= 0){ const double* X = ws + MAT0 + (size_t)s4 * MATD; r += a4*X[ij]; m += a4*X[NN+ij]; }
    if (i == j) r += g;
    C[ij] = r; C[NN + ij] = m;
}

__global__ void k_expm_prep(double* ws)
{
    if (threadIdx.x == 0 && blockIdx.x == 0){
        double n1 = ws[8];
        int s = 0;
        if (n1 > 0.5){
            s = (int)ceil(log2(n1 / 0.5));
            if (s < 0) s = 0; if (s > 10) s = 10;
        }
        ws[SC_EXPM_S] = (double)s;
        ws[SC_EXPM_SCALE] = ldexp(1.0, -s);
    }
}

// ==================== cooperative logm kernel ====================
// 2 DB-sqrt stages (NS inversions, warm-started when ||M-I||<0.9) +
// 2 inverse-free Newton-Schulz sqrt stages + Cayley + adaptive artanh + S.
// 256 blocks x 512 threads; lean ws-based grid barrier (gbar) between phases.
struct ShMemC {
    double Ar[2][16][17], Ai[2][16][17], Br[2][16][17], Bi[2][16][17];
    double redA[512];
    double redB[256];
};

__global__ __launch_bounds__(512, 2) void k_logm_coop(double* __restrict__ ws)
{
    __shared__ ShMemC sh;
    unsigned int* bar = (unsigned int*)(ws + BARBASE);
    unsigned int bgen = 0;
    const int t = threadIdx.x;
    const int b = blockIdx.x;
    const int team = t >> 8, tt = t & 255;
    const int tx = tt & 15, ty = tt >> 4;
    const int bx = b & 15, by = b >> 4;
    const int row = by*16 + ty, col = bx*16 + tx;
    const int ij2 = b*512 + t;                   // 0..131071: both planes
    const int pl = ij2 >> 16;                    // 0 re, 1 im
    const int lin = ij2 & 65535;
    const int li = lin >> 8, lj = lin & 255;
    const int tr_idx = (lj << 8) + li + (pl ? NN : 0);   // transposed index
    const bool diagre = (pl == 0) && (li == lj);

    double* const MB = ws + MAT0;
    auto SL = [&](int s){ return MB + (size_t)s * MATD; };
    auto GS = [&](){ gbar(bar, bgen); };

    // grid-uniform max over a 256-entry ws array
    auto bmax = [&](int base) -> double {
        sh.redA[t] = ws[base + (t & 255)];
        __syncthreads();
        for (int s = 256; s > 0; s >>= 1){
            if (t < s) sh.redA[t] = fmax(sh.redA[t], sh.redA[t+s]);
            __syncthreads();
        }
        double r = sh.redA[0]; __syncthreads();
        return r;
    };

    // block b computes row-b and col-b abs sums (and optionally |M-I| row sum)
    auto partials = [&](const double* M, bool withDev){
        double v, dv = 0.0;
        if (t < 256){
            double e = M[b*256 + t], f = M[NN + b*256 + t];
            v = fabs(e) + fabs(f);
            if (withDev) dv = fabs(e - ((b == t) ? 1.0 : 0.0)) + fabs(f);
        } else {
            int c2 = t - 256;
            v = fabs(M[c2*256 + b]) + fabs(M[NN + c2*256 + b]);
        }
        sh.redA[t] = v;
        if (t < 256) sh.redB[t] = dv;
        __syncthreads();
        for (int s = 128; s > 0; s >>= 1){
            if (t < s){ sh.redA[t] += sh.redA[t+s]; sh.redB[t] += sh.redB[t+s]; }
            else if (t >= 256 && t < 256 + s){ sh.redA[t] += sh.redA[t+s]; }
            __syncthreads();
        }
        if (t == 0){ ws[NRM_ROW + b] = sh.redA[0]; if (withDev) ws[NRM_DEV + b] = sh.redB[0]; }
        if (t == 256){ ws[NRM_COL + b] = sh.redA[256]; }
        __syncthreads();
    };

    // C = alpha*preA(A)*preB(B) + gamma*I ; split-k x2 across teams.
    // preA: 0 none, 1 conj, 2 (A-I), 3 (3I-A). preB: 0 none, 1 (2I-B), 2 (3I-B).
    auto gemm = [&](const double* A, const double* B, double* C,
                    int preA, int preB, double alpha, double gamma, double* tr){
        double cr = 0.0, ci = 0.0;
        for (int s = 0; s < 8; s++){
            int kb = (team << 7) + (s << 4);
            int ac = kb + tx;
            double a_re = A[row*256 + ac], a_im = A[NN + row*256 + ac];
            if (preA == 1) a_im = -a_im;
            else if (preA == 2){ if (row == ac) a_re -= 1.0; }
            else if (preA == 3){ a_re = ((row == ac) ? 3.0 : 0.0) - a_re; a_im = -a_im; }
            int br = kb + ty;
            double b_re = B[br*256 + col], b_im = B[NN + br*256 + col];
            if (preB == 1){ b_re = ((br == col) ? 2.0 : 0.0) - b_re; b_im = -b_im; }
            else if (preB == 2){ b_re = ((br == col) ? 3.0 : 0.0) - b_re; b_im = -b_im; }
            sh.Ar[team][ty][tx] = a_re; sh.Ai[team][ty][tx] = a_im;
            sh.Br[team][ty][tx] = b_re; sh.Bi[team][ty][tx] = b_im;
            __syncthreads();
            #pragma unroll
            for (int kk = 0; kk < 16; kk++){
                double xr = sh.Ar[team][ty][kk], xi = sh.Ai[team][ty][kk];
                double yr = sh.Br[team][kk][tx], yi = sh.Bi[team][kk][tx];
                cr += xr*yr - xi*yi;
                ci += xr*yi + xi*yr;
            }
            __syncthreads();
        }
        if (team == 1){ sh.Ar[1][ty][tx] = cr; sh.Ai[1][ty][tx] = ci; }
        __syncthreads();
        if (team == 0){
            cr += sh.Ar[1][ty][tx]; ci += sh.Ai[1][ty][tx];
            cr *= alpha; ci *= alpha;
            if (row == col) cr += gamma;
            C[row*256 + col] = cr;
            C[NN + row*256 + col] = ci;
            if (tr && row == col){ atomicAdd(tr, cr); atomicAdd(tr + 1, ci); }
        }
        __syncthreads();
    };

    double* dMm = SL(S_M);  double* dM2 = SL(S_M2);
    double* dYy = SL(S_Y);  double* dY2 = SL(S_Y2);
    double* dX  = SL(S_X);  double* dX2 = SL(S_X2);
    double* dT  = SL(S_T);
    double* dG  = SL(S_G);  double* dG2 = SL(S_G2);
    double* dW  = SL(S_W);  double* dV  = SL(S_V);
    double* dLT = SL(S_LAT);
    double* dS  = SL(PBASE);

    int invid = 0;
    // NS inverse of src. Requires NRM_ROW/COL (norms of src) synced.
    // dev = ||src - I||inf (warm start when < 0.9). Returns buffer with inverse.
    auto inv = [&](const double* src, double dev, int maxit,
                   double& n1, double& ninf) -> double* {
        n1 = bmax(NRM_COL); ninf = bmax(NRM_ROW);
        if (dev < 0.9){
            double v = -src[ij2];
            if (diagre) v += 2.0;
            dX[ij2] = v;                         // X0 = 2I - src (resid dev^2)
        } else {
            double nu = 1.0 / (n1 * ninf);
            double v = src[tr_idx] * nu;
            dX[ij2] = pl ? -v : v;               // X0 = conj(src)^T * nu
        }
        GS();
        double* xc = dX; double* xo = dX2;
        for (int i2 = 0; i2 < maxit; i2++){
            double* tr = ws + (TRBASE + invid*96 + 2*i2);  // pre-zeroed
            gemm(src, xc, dT, 0, 0, 1.0, 0.0, tr);         // T = M X (+trace)
            GS();
            double resid = fabs(256.0 - tr[0]) + fabs(tr[1]);
            if (resid < 2.56e-8) break;
            gemm(xc, dT, xo, 0, 1, 1.0, 0.0, nullptr);     // X' = X (2I - T)
            GS();
            double* tm = xc; xc = xo; xo = tm;
        }
        invid++;
        return xc;
    };

    double* bcur = SL(S_EW);

    // ---- 2 scaled product-form DB sqrt stages (handle full spectrum) ----
    for (int st = 0; st < 2; st++){
        dMm[ij2] = bcur[ij2];
        dYy[ij2] = bcur[ij2];
        partials(bcur, true);
        GS();
        double* mc = dMm; double* mo = dM2; double* yc = dYy; double* yo = dY2;
        double dev = bmax(NRM_DEV);
        for (int it = 0; it < 24; it++){
            if (dev < 1e-9) break;
            double nm1, nminf;
            double* iy = inv(mc, dev, 48, nm1, nminf);
            partials(iy, false);
            GS();
            double ni1 = bmax(NRM_COL), niinf = bmax(NRM_ROW);
            double mu = pow((ni1 * niinf) / (nm1 * nminf), 0.125);
            if (!(mu > 0.125)) mu = 0.125;
            if (mu > 8.0) mu = 8.0;
            double mu2 = mu*mu, rmu = 1.0/mu, rmu2 = rmu*rmu;
            gemm(yc, iy, dG, 0, 0, 1.0, 0.0, nullptr);     // G = Y * M^-1
            {   // M' = 0.25*(mu^2 M + mu^-2 M^-1) + 0.5 I
                double r = 0.25 * (mu2 * mc[ij2] + rmu2 * iy[ij2]);
                if (diagre) r += 0.5;
                mo[ij2] = r;
            }
            GS();
            yo[ij2] = 0.5 * (mu * yc[ij2] + rmu * dG[ij2]); // Y' = 0.5(mu Y + G/mu)
            partials(mo, true);
            GS();
            dev = bmax(NRM_DEV);
            double* tm = mc; mc = mo; mo = tm;
            tm = yc; yc = yo; yo = tm;
        }
        bcur = yc;
    }

    // ---- 2 inverse-free Newton-Schulz sqrt stages ----
    // input spectrum has |arg| < pi/4 -> rho(I - B/c) < 1 guaranteed for
    // c = sqrt(n1*ninf) >= sigma_max.
    for (int st = 0; st < 2; st++){
        partials(bcur, false);
        GS();
        double c = sqrt(bmax(NRM_COL) * bmax(NRM_ROW));
        double invc = 1.0 / c, sc = sqrt(c);
        dYy[ij2] = bcur[ij2] * invc;                       // Y0 = B/c
        dX[ij2]  = diagre ? 1.0 : 0.0;                     // Z0 = I
        GS();
        double* Ycur = dYy; double* Yalt = dY2;
        double* Zcur = dX;  double* Zalt = dX2;
        for (int it = 0; it < 30; it++){
            gemm(Zcur, Ycur, dT, 0, 0, 1.0, 0.0, nullptr); // E = Z Y
            GS();
            partials(dT, true);                            // ||E - I||inf
            GS();
            double dv = bmax(NRM_DEV);
            if (dv < 1e-11) break;
            gemm(Ycur, dT, Yalt, 0, 2, 0.5, 0.0, nullptr); // Y' = 0.5 Y (3I - E)
            gemm(dT, Zcur, Zalt, 3, 0, 0.5, 0.0, nullptr); // Z' = 0.5 (3I - E) Z
            GS();
            double* tm = Ycur; Ycur = Yalt; Yalt = tm;
            tm = Zcur; Zcur = Zalt; Zalt = tm;
        }
        dMm[ij2] = sc * Ycur[ij2];                         // B_{s+1} = sqrt(c) Y
        GS();
        bcur = dMm;
    }

    // ---- Cayley: W = (B - I)(B + I)^-1 ----
    dG[ij2] = bcur[ij2] + (diagre ? 1.0 : 0.0);            // G = B + I
    GS();
    partials(dG, true);
    GS();
    double devG = bmax(NRM_DEV);
    double cn1, cninf;
    double* giy = inv(dG, devG, 48, cn1, cninf);
    gemm(bcur, giy, dW, 2, 0, 1.0, 0.0, nullptr);          // W = (B-I)(B+I)^-1
    GS();
    gemm(dW, dW, dV, 0, 0, 1.0, 0.0, nullptr);             // V = W^2
    partials(dW, false);                                   // ||W||inf for degree
    GS();
    double nW = bmax(NRM_ROW);
    // adaptive odd-series degree: tail <= q^{J+1}/(1-q), q = ||V|| <= nW^2
    double q = nW * nW;
    int J = 19;
    if (q < 0.5){
        J = 1;
        double qp = q * q;     // q^{J+1}
        while (J < 19 && qp >= 1e-16 * (1.0 - q)){ qp *= q; J++; }
    }
    dG[ij2] = diagre ? 1.0/(double)(2*J + 1) : 0.0;        // Horner seed
    GS();
    double* gc = dG; double* go = dG2;
    for (int j = J - 1; j >= 0; j--){
        gemm(dV, gc, go, 0, 0, 1.0, 1.0/(double)(2*j + 1), nullptr);
        GS();
        double* tm = gc; gc = go; go = tm;
    }
    gemm(dW, gc, dLT, 0, 0, 1.0, 0.0, nullptr);            // LAT = artanh(W)
    GS();
    // S = LOG_SCALE * conj(LAT - LAT^T)
    {
        double vv = dLT[ij2] - dLT[tr_idx];
        dS[ij2] = pl ? -LOG_SCALE * vv : LOG_SCALE * vv;
    }
}

// theta per u (rigorous upper bound); theta>4 -> scaling+squaring pool
__global__ __launch_bounds__(256) void k_theta_pool(double* ws)
{
    __shared__ double th[256]; __shared__ int rk[256];
    int t = threadIdx.x;
    double nS = ws[SC_NORMS2];
    double cr = ws[W_C_RE + t], ci = ws[W_C_IM + t];
    th[t] = sqrt(cr*cr + ci*ci) * nS;
    __syncthreads();
    int r = 0;
    for (int v = 0; v < 256; v++){
        if (th[v] > th[t] || (th[v] == th[t] && v < t)) r++;
    }
    rk[t] = r;
    __syncthreads();
    if (t == 0){
        int cnt = 0;
        for (int u = 0; u < 256; u++){
            double s = 0.0; int slot = -1;
            if (th[u] > 4.0 && rk[u] < NPOOL){
                double e = ceil(log2(th[u] / 4.0));
                if (e < 1.0) e = 1.0; if (e > 12.0) e = 12.0;
                s = e; slot = cnt;
                ws[W_SLOTU + cnt] = (double)u;
                cnt++;
            }
            ws[W_SU + u] = s;
            ws[W_SLOT + u] = (double)slot;
        }
        for (int k = cnt; k < NPOOL; k++) ws[W_SLOTU + k] = -1.0;
    }
}

// weights w[u][k] = (c_u / 2^{s_u})^k / k!
__global__ __launch_bounds__(256) void k_weights(double* ws)
{
    int u = threadIdx.x;
    double sc = ldexp(1.0, -(int)ws[W_SU + u]);
    double cr = ws[W_C_RE + u] * sc, ci = ws[W_C_IM + u] * sc;
    double wr = 1.0, wi = 0.0;
    ws[W_W + (u*33)*2] = 1.0; ws[W_W + (u*33)*2 + 1] = 0.0;
    for (int k = 1; k <= 32; k++){
        double inv = 1.0 / (double)k;
        double nr = (wr*cr - wi*ci) * inv, ni = (wr*ci + wi*cr) * inv;
        wr = nr; wi = ni;
        ws[W_W + (u*33 + k)*2] = wr;
        ws[W_W + (u*33 + k)*2 + 1] = wi;
    }
}

// exp_tens[u] = sum_k w[u][k] S^k -> f32 out (non-pooled) or fp64 pool base
__global__ __launch_bounds__(256) void k_combo(double* ws, float* out, long off_ex, int f,
                                               int pass, int K)
{
    __shared__ double wre[16][33], wim[16][33];
    __shared__ int anywork;
    int t = threadIdx.x;
    int row = blockIdx.x, ug = blockIdx.y;
    if (t == 0) anywork = (pass == 0) ? 1 : 0;
    __syncthreads();
    if (pass > 0 && t < 16){
        int u = ug*16 + t;
        int slot = (int)ws[W_SLOT + u];
        int phys = slot - pass * K;
        if (slot >= 0 && phys >= 0 && phys < K) anywork = 1;
    }
    __syncthreads();
    if (!anywork) return;
    for (int i = t; i < 16*33; i += 256){
        int g = i / 33, k = i % 33;
        int u = ug*16 + g;
        wre[g][k] = ws[W_W + (u*33 + k)*2];
        wim[g][k] = ws[W_W + (u*33 + k)*2 + 1];
    }
    __syncthreads();
    int j = t, ij = row*256 + j;
    double ar[16], ai[16];
    #pragma unroll
    for (int g = 0; g < 16; g++){
        ar[g] = (row == j) ? wre[g][0] : 0.0;
        ai[g] = (row == j) ? wim[g][0] : 0.0;
    }
    for (int k = 1; k <= 32; k++){
        const double* SP = ws + MAT0 + (size_t)(PBASE + k - 1) * MATD;
        double sre = SP[ij], sim = SP[NN + ij];
        #pragma unroll
        for (int g = 0; g < 16; g++){
            ar[g] += wre[g][k]*sre - wim[g][k]*sim;
            ai[g] += wre[g][k]*sim + wim[g][k]*sre;
        }
    }
    for (int g = 0; g < 16; g++){
        int u = ug*16 + g;
        int slot = (int)ws[W_SLOT + u];
        if (slot >= 0){
            int phys = slot - pass * K;
            if (phys >= 0 && phys < K){
                double* P = ws + MAT0 + (size_t)(POOL0 + phys) * MATD;
                P[ij] = ar[g]; P[NN + ij] = ai[g];
            }
        } else if (pass == 0){
            long base = off_ex + (long)u * NN * f + (long)ij * f;
            out[base] = (float)ar[g];
            if (f == 2) out[base + 1] = (float)ai[g];
        }
    }
}

// pool squaring
__global__ __launch_bounds__(256) void k_pool_sq(double* ws, int round, int pass, int K)
{
    int z = blockIdx.z;
    int vs = pass * K + z;
    int u = (vs < NPOOL) ? (int)ws[W_SLOTU + vs] : -1;
    if (u < 0) return;
    if (round > (int)ws[W_SU + u]) return;
    const double* A = ws + MAT0 + (size_t)(POOL0 + ((round & 1) ? 0 : K) + z) * MATD;
    double* C = ws + MAT0 + (size_t)(POOL0 + ((round & 1) ? K : 0) + z) * MATD;
    int tx = threadIdx.x & 15, ty = threadIdx.x >> 4;
    int row = blockIdx.y*16 + ty, col = blockIdx.x*16 + tx;
    __shared__ double Asr[16][17], Asi[16][17], Bsr[16][17], Bsi[16][17];
    double cr = 0.0, ci = 0.0;
    for (int k0 = 0; k0 < 256; k0 += 16){
        Asr[ty][tx] = A[row*256 + k0 + tx];
        Asi[ty][tx] = A[NN + row*256 + k0 + tx];
        Bsr[ty][tx] = A[(k0 + ty)*256 + col];
        Bsi[ty][tx] = A[NN + (k0 + ty)*256 + col];
        __syncthreads();
        #pragma unroll
        for (int kk = 0; kk < 16; kk++){
            double xr = Asr[ty][kk], xi = Asi[ty][kk];
            double yr = Bsr[kk][tx], yi = Bsi[kk][tx];
            cr += xr*yr - xi*yi;
            ci += xr*yi + xi*yr;
        }
        __syncthreads();
    }
    C[row*256 + col] = cr;
    C[NN + row*256 + col] = ci;
}

__global__ __launch_bounds__(256) void k_pool_out(const double* ws, float* out, long off_ex,
                                                  int f, int pass, int K)
{
    int z = blockIdx.y;
    int vs = pass * K + z;
    int u = (vs < NPOOL) ? (int)ws[W_SLOTU + vs] : -1;
    if (u < 0) return;
    int su = (int)ws[W_SU + u];
    int ij = blockIdx.x * 256 + threadIdx.x;
    const double* P = ws + MAT0 + (size_t)(POOL0 + ((su & 1) ? K : 0) + z) * MATD;
    long base = off_ex + (long)u * NN * f + (long)ij * f;
    out[base] = (float)P[ij];
    if (f == 2) out[base + 1] = (float)P[NN + ij];
}

__global__ __launch_bounds__(256) void k_cast_out(const double* ws, int slot, float* out, long off, int f)
{
    int ij = blockIdx.x * 256 + threadIdx.x;
    const double* P = ws + MAT0 + (size_t)slot * MATD;
    out[off + (long)ij * f] = (float)P[ij];
    if (f == 2) out[off + (long)ij * f + 1] = (float)P[NN + ij];
}

// ============================ host ============================
extern "C" void kernel_launch(void* const* d_in, const int* in_sizes, int n_in,
                              void* d_out, int out_size, void* d_ws, size_t ws_size,
                              hipStream_t stream)
{
    double* ws = (double*)d_ws;
    float* out = (float*)d_out;

    int f = (out_size >= 33816832) ? 2 : 1;
    long off_ex = 256;
    long off_uw = off_ex + (long)f * 16777216L;
    long off_ew = off_uw + (long)f * 65536L;

    k_init<<<128, 256, 0, stream>>>(ws);
    k_detect<<<1, 64, 0, stream>>>(d_in[0], ws);
    k_small<<<1, 256, 0, stream>>>(d_in[0], d_in[1], d_in[2], d_in[3], d_in[4], ws, out);

    long slotsAvail = (long)(ws_size / 8 - MAT0) / MATD;
    if (slotsAvail < POOL0 + 32) return;
    int K = (int)((slotsAvail - POOL0) / 2);
    if (K > NPOOL) K = NPOOL;
    if (K < 16) K = 16;
    int P = (NPOOL + K - 1) / K;

    auto MP = [&](int s){ return ws + MAT0 + (size_t)s * MATD; };
    auto ZG = [&](int a, int b, int c, int preA, int preB, double al, double be,
                  int d, double ga, int fm, int round){
        k_zgemm<<<dim3(16,16,1), 256, 0, stream>>>(MP(a), MP(b), MP(c),
            d >= 0 ? MP(d) : nullptr, preA, preB, al, be, ga, ws,
            fm, round, 0, 0, 0L, 0L, 0L);
    };
    auto GEMM = [&](int a, int b, int c, int preA, int preB, double al, double be, int d, double ga){
        ZG(a, b, c, preA, preB, al, be, d, ga, 0, 0);
    };

    k_build_mats<<<256, 256, 0, stream>>>(d_in[5], d_in[6], d_in[7], d_in[8], ws);
    k_cast_out<<<256, 256, 0, stream>>>(ws, S_NUW, out, off_uw, f);

    // -------- expm(new_uw): scaling + Paterson-Stockmeyer deg-16 Taylor + squarings ----
    static const double INVF[17] = {
        1.0, 1.0, 0.5, 1.0/6.0, 1.0/24.0, 1.0/120.0, 1.0/720.0, 1.0/5040.0,
        1.0/40320.0, 1.0/362880.0, 1.0/3628800.0, 1.0/39916800.0, 1.0/479001600.0,
        1.0/6227020800.0, 1.0/87178291200.0, 1.0/1307674368000.0, 1.0/20922789888000.0 };
    k_norm1inf<<<1, 256, 0, stream>>>(MP(S_NUW), ws, 8);
    k_expm_prep<<<1, 64, 0, stream>>>(ws);
    k_combine<<<256, 256, 0, stream>>>(ws, S_LAT, S_NUW, -1, -1, -1, 1.0, 0, 0, 0, 0.0, 1);
    GEMM(S_LAT, S_LAT, S_T2, 0, 0, 1.0, 0.0, -1, 0.0);
    GEMM(S_T2, S_LAT, S_T3, 0, 0, 1.0, 0.0, -1, 0.0);
    GEMM(S_T2, S_T2, S_T4, 0, 0, 1.0, 0.0, -1, 0.0);
    k_combine<<<256, 256, 0, stream>>>(ws, S_E1, -1, -1, -1, -1, 0, 0, 0, 0, INVF[16], 0);
    for (int b = 3; b >= 0; b--){
        GEMM(S_T4, S_E1, S_E2, 0, 0, 1.0, 0.0, -1, 0.0);
        k_combine<<<256, 256, 0, stream>>>(ws, S_E1, S_E2, S_LAT, S_T2, S_T3,
            1.0, INVF[4*b+1], INVF[4*b+2], INVF[4*b+3], INVF[4*b], 0);
    }
    for (int r = 1; r <= 10; r++){
        int src = (r & 1) ? S_E1 : S_E2, dst = (r & 1) ? S_E2 : S_E1;
        ZG(src, src, dst, 0, 0, 1.0, 0.0, -1, 0.0, 1, r);
    }
    GEMM(S_EW, S_E1, S_M2, 1, 0, 1.0, 0.0, -1, 0.0);   // new_Ew = conj(Ew) expm(new_uw)
    k_cast_out<<<256, 256, 0, stream>>>(ws, S_M2, out, off_ew, f);

    // -------- logm(Ew): one cooperative kernel (lean ws-based barrier) --------
    {
        void* cargs[] = { (void*)&ws };
        hipLaunchCooperativeKernel((void*)k_logm_coop, dim3(256), dim3(512),
                                   cargs, 0, stream);
    }

    // -------- batched exp_tens = expm(c_u S): shared powers + pooled squaring --------
    k_norm1inf<<<1, 256, 0, stream>>>(MP(PBASE), ws, 12);
    k_fro<<<1, 256, 0, stream>>>(MP(PBASE), ws);
    k_snorm<<<1, 1, 0, stream>>>(ws);
    k_theta_pool<<<1, 256, 0, stream>>>(ws);
    k_weights<<<1, 256, 0, stream>>>(ws);
    for (int m = 1; m < 32; m *= 2){
        int cnt = (m < 32 - m) ? m : (32 - m);
        k_zgemm<<<dim3(16,16,cnt), 256, 0, stream>>>(MP(PBASE + m - 1), MP(PBASE), MP(PBASE + m),
            nullptr, 0, 0, 1.0, 0.0, 0.0, ws, 0, 0, 0, 0, 0L, MATD, MATD);
    }
    for (int p = 0; p < P; p++){
        k_combo<<<dim3(256,16), 256, 0, stream>>>(ws, out, off_ex, f, p, K);
        for (int r = 1; r <= 12; r++)
            k_pool_sq<<<dim3(16,16,K), 256, 0, stream>>>(ws, r, p, K);
        k_pool_out<<<dim3(256,K), 256, 0, stream>>>(ws, out, off_ex, f, p, K);
    }
}